// Round 9
// baseline (505.992 us; speedup 1.0000x reference)
//
#include <hip/hip_runtime.h>
#include <math.h>

#define BATCH   64
#define DIMC    384
#define KEY_DIM 16
#define HEADS   8
#define DD      64
#define DH      512
#define NH_KD   128
#define RES     28
#define RES2    14
#define NN      784
#define NN2     196
#define OUT_DIM 384
#define SCALE   0.25f
#define XPAD    896     // 7*128
#define QPAD    256     // 2*128
#define KPAD    832     // 13*64

typedef __attribute__((ext_vector_type(8))) short bf16x8;
typedef __attribute__((ext_vector_type(4))) float f32x4;

#define MFMA32(a, b, c) __builtin_amdgcn_mfma_f32_16x16x32_bf16(a, b, c, 0, 0, 0)

__device__ inline short f2bf(float f) {
    unsigned u = __float_as_uint(f);
    unsigned r = (u + 0x7fff + ((u >> 16) & 1)) >> 16;
    return (short)r;
}
__device__ inline float bf2f(short h) {
    return __uint_as_float(((unsigned)(unsigned short)h) << 16);
}

// ---- ws byte offsets ----
#define O_QINT_HI  20971520u    // bf16 qinT [b][256][384] (step 1 -> 3)
#define O_XT_HI    0u           // bf16 xT [b][896][384] (step 4 -> 6)
#define O_QT       88080384u    // packed QT (step 3 -> 9)
#define O_KT       96468992u    // packed KT (step 5 -> 9)
#define O_V        123731968u   // bf16 V [b][512][832] (step 6 -> 9)
#define O_VLOCAL   178257920u   // fp32 (step 7 -> 10)
#define O_BIASB    203948032u   // bf16 (step 8 -> 9)
#define O_W_HI     206557184u
#define O_W_LO     207540224u
#define O_ATTNT    0u           // fp32 (step 9 -> 10; xT dead)
#define O_GT_HI    25690112u    // (step 10 -> 11)
#define O_GT_LO    42467328u

// ---------------- qinT = f2bf(dwconv3x3 s2 (pad 1) + pool), transposed [b][QPAD][C] ----------------
__global__ void qinT_kernel(const float* __restrict__ x, const float* __restrict__ ql_w,
                            const float* __restrict__ ql_b, short* __restrict__ qinT) {
    int c = blockIdx.x, b = blockIdx.y, n2 = threadIdx.x;
    if (n2 >= NN2) return;
    int i = n2 / RES2, j = n2 % RES2;
    const float* xp = x + ((size_t)b * DIMC + c) * (RES * RES);
    const float* w  = ql_w + c * 9;
    float acc = ql_b[c];
    #pragma unroll
    for (int di = 0; di < 3; ++di) {
        int r = 2 * i + di - 1;
        if (r < 0 || r >= RES) continue;
        #pragma unroll
        for (int dj = 0; dj < 3; ++dj) {
            int cc = 2 * j + dj - 1;
            if (cc < 0 || cc >= RES) continue;
            acc += xp[r * RES + cc] * w[di * 3 + dj];
        }
    }
    acc += xp[(2 * i) * RES + 2 * j];
    qinT[((size_t)b * QPAD + n2) * DIMC + c] = f2bf(acc);
}

// ---------------- weight split ----------------
__global__ void wsplit_kernel(const float* __restrict__ w0, const float* __restrict__ w1,
                              const float* __restrict__ w2, const float* __restrict__ w3,
                              short* __restrict__ hi, short* __restrict__ lo) {
    int i = blockIdx.x * 256 + threadIdx.x;
    if (i >= 491520) return;
    const float* src; int j = i;
    if (j < 49152) src = w0;
    else if (j < 98304) { src = w1; j -= 49152; }
    else if (j < 294912) { src = w2; j -= 98304; }
    else { src = w3; j -= 294912; }
    float v = src[j];
    short h = f2bf(v);
    hi[i] = h;
    lo[i] = f2bf(v - bf2f(h));
}

// ---------------- transpose + bf16: [b][C][N] f32 -> [b][Npad][C] bf16 ----------------
__global__ void tsplit_kernel(const float* __restrict__ in, short* __restrict__ out_hi,
                              int C, int N, int Npad) {
    __shared__ float tile[32][33];
    int ntb = blockIdx.x * 32, ctb = blockIdx.y * 32, b = blockIdx.z;
    int tn = threadIdx.x & 31, tc4 = threadIdx.x >> 5;
    #pragma unroll
    for (int i = 0; i < 4; ++i) {
        int c = tc4 + i * 8;
        int n = ntb + tn;
        tile[c][tn] = (n < N) ? in[((size_t)b * C + ctb + c) * N + n] : 0.f;
    }
    __syncthreads();
    int tc = threadIdx.x & 31, tn4 = threadIdx.x >> 5;
    #pragma unroll
    for (int i = 0; i < 4; ++i) {
        int n = tn4 + i * 8;
        out_hi[((size_t)b * Npad + ntb + n) * C + ctb + tc] = f2bf(tile[tc][n]);
    }
}

// ---------------- split-bf16 MFMA GEMM ----------------
// A = weights hi/lo; B = activations hi (+lo if BLO)
// mode 0: fp32 [b][O][Nn]; mode 1: bf16 [b][O][NPADo] zero-padded;
// mode 2: packed [b*8+h][NPADo][16hi|16lo] (O=128), value scaled by pscale
template<bool BLO>
__global__ __launch_bounds__(256)
void gemm_split_kernel(const short* __restrict__ Ag_hi, const short* __restrict__ Ag_lo,
                       const short* __restrict__ Bg_hi, const short* __restrict__ Bg_lo,
                       const float* __restrict__ bias, const float* __restrict__ s,
                       const float* __restrict__ off,
                       float* __restrict__ out_f, short* __restrict__ out_b,
                       int mode, int C, int Nn, int Npad, int NPADo, float pscale) {
    __shared__ __align__(16) short Ah[128 * 32], Al[128 * 32], Bh[128 * 32];
    __shared__ __align__(16) short Bl[BLO ? 128 * 32 : 64];

    const int t = threadIdx.x;
    const int n0 = blockIdx.x * 128, o0 = blockIdx.y * 128, b = blockIdx.z;
    const int O = gridDim.y * 128;
    const int lane = t & 63, wid = t >> 6;
    const int wm = wid & 1, wn = wid >> 1;
    const int lr = lane & 15, kg = lane >> 4;

    f32x4 acc[4][4];
    #pragma unroll
    for (int m = 0; m < 4; ++m)
        #pragma unroll
        for (int n = 0; n < 4; ++n)
            acc[m][n] = (f32x4){0.f, 0.f, 0.f, 0.f};

    const int srow = t >> 2;
    const int sch  = (t & 3) * 8;
    const size_t aBase = (size_t)(o0 + srow) * C + sch;
    const size_t bBase = ((size_t)b * Npad + n0 + srow) * C + sch;
    const size_t rstep = (size_t)64 * C;

    bf16x8 rA[2], rAl[2], rB[2], rBl[2];
    #pragma unroll
    for (int p = 0; p < 2; ++p) {
        rA[p]  = *(const bf16x8*)(Ag_hi + aBase + p * rstep);
        rAl[p] = *(const bf16x8*)(Ag_lo + aBase + p * rstep);
        rB[p]  = *(const bf16x8*)(Bg_hi + bBase + p * rstep);
        if constexpr (BLO) rBl[p] = *(const bf16x8*)(Bg_lo + bBase + p * rstep);
    }

    for (int k0 = 0;; k0 += 32) {
        #pragma unroll
        for (int p = 0; p < 2; ++p) {
            int la = (srow + p * 64) * 32 + sch;
            *(bf16x8*)&Ah[la] = rA[p];
            *(bf16x8*)&Al[la] = rAl[p];
            *(bf16x8*)&Bh[la] = rB[p];
            if constexpr (BLO) *(bf16x8*)&Bl[la] = rBl[p];
        }
        __syncthreads();

        if (k0 + 32 < C) {
            #pragma unroll
            for (int p = 0; p < 2; ++p) {
                rA[p]  = *(const bf16x8*)(Ag_hi + aBase + (k0 + 32) + p * rstep);
                rAl[p] = *(const bf16x8*)(Ag_lo + aBase + (k0 + 32) + p * rstep);
                rB[p]  = *(const bf16x8*)(Bg_hi + bBase + (k0 + 32) + p * rstep);
                if constexpr (BLO) rBl[p] = *(const bf16x8*)(Bg_lo + bBase + (k0 + 32) + p * rstep);
            }
        }

        bf16x8 ah[4], al[4];
        #pragma unroll
        for (int m = 0; m < 4; ++m) {
            int row = wm * 64 + m * 16 + lr;
            ah[m] = *(const bf16x8*)&Ah[row * 32 + kg * 8];
            al[m] = *(const bf16x8*)&Al[row * 32 + kg * 8];
        }
        #pragma unroll
        for (int nf = 0; nf < 4; ++nf) {
            int row = wn * 64 + nf * 16 + lr;
            bf16x8 bh = *(const bf16x8*)&Bh[row * 32 + kg * 8];
            #pragma unroll
            for (int m = 0; m < 4; ++m) {
                acc[m][nf] = MFMA32(ah[m], bh, acc[m][nf]);
                acc[m][nf] = MFMA32(al[m], bh, acc[m][nf]);
            }
            if constexpr (BLO) {
                bf16x8 bl = *(const bf16x8*)&Bl[row * 32 + kg * 8];
                #pragma unroll
                for (int m = 0; m < 4; ++m)
                    acc[m][nf] = MFMA32(ah[m], bl, acc[m][nf]);
            }
        }
        if (k0 + 32 >= C) break;
        __syncthreads();
    }

    #pragma unroll
    for (int m = 0; m < 4; ++m) {
        #pragma unroll
        for (int nf = 0; nf < 4; ++nf) {
            int col = n0 + wn * 64 + nf * 16 + lr;
            if (mode == 0) {
                if (col >= Nn) continue;
                #pragma unroll
                for (int r = 0; r < 4; ++r) {
                    int row = o0 + wm * 64 + m * 16 + kg * 4 + r;
                    float a = s[row];
                    out_f[((size_t)b * O + row) * Nn + col] =
                        acc[m][nf][r] * a + (bias[row] * a + off[row]);
                }
            } else if (mode == 1) {
                if (col >= NPADo) continue;
                #pragma unroll
                for (int r = 0; r < 4; ++r) {
                    int row = o0 + wm * 64 + m * 16 + kg * 4 + r;
                    short hv = 0;
                    if (col < Nn) {
                        float a = s[row];
                        hv = f2bf(acc[m][nf][r] * a + (bias[row] * a + off[row]));
                    }
                    out_b[((size_t)b * O + row) * NPADo + col] = hv;
                }
            } else {
                if (col >= NPADo) continue;
                int hh = (o0 + wm * 64 + m * 16) >> 4;
                short4 h4, l4;
                #pragma unroll
                for (int r = 0; r < 4; ++r) {
                    int row = o0 + wm * 64 + m * 16 + kg * 4 + r;
                    float v = 0.f;
                    if (col < Nn) {
                        float a = s[row];
                        v = (acc[m][nf][r] * a + (bias[row] * a + off[row])) * pscale;
                    }
                    short hv = f2bf(v);
                    ((short*)&h4)[r] = hv;
                    ((short*)&l4)[r] = f2bf(v - bf2f(hv));
                }
                size_t base = ((size_t)(b * 8 + hh) * NPADo + col) * 32 + kg * 4;
                *(short4*)(out_b + base)      = h4;
                *(short4*)(out_b + base + 16) = l4;
            }
        }
    }
}

// ---------------- v_local ----------------
__global__ void vlocal_kernel(const short* __restrict__ v,
                              const float* __restrict__ vl_w, const float* __restrict__ vl_b,
                              const float* __restrict__ vl_s, const float* __restrict__ vl_o,
                              float* __restrict__ vlocal) {
    int c = blockIdx.x, b = blockIdx.y, n2 = threadIdx.x;
    if (n2 >= NN2) return;
    int i = n2 / RES2, j = n2 % RES2;
    const size_t base = ((size_t)b * DH + c) * KPAD;
    const float* w = vl_w + c * 9;
    float acc = vl_b[c];
    #pragma unroll
    for (int di = 0; di < 3; ++di) {
        int r = 2 * i + di - 1;
        if (r < 0 || r >= RES) continue;
        #pragma unroll
        for (int dj = 0; dj < 3; ++dj) {
            int cc = 2 * j + dj - 1;
            if (cc < 0 || cc >= RES) continue;
            acc += bf2f(v[base + r * RES + cc]) * w[di * 3 + dj];
        }
    }
    vlocal[((size_t)b * DH + c) * NN2 + n2] = acc * vl_s[c] + vl_o[c];
}

// ---------------- bias expand -> bf16, padded rows of 832 ----------------
__global__ void biasB_expand_kernel(const float* __restrict__ ab, const int* __restrict__ bidx,
                                    short* __restrict__ biasB, int n_off) {
    int i = blockIdx.x * 256 + threadIdx.x;
    int h = blockIdx.y;
    if (i >= NN2 * KPAD) return;
    int q = i / KPAD, key = i - q * KPAD;
    short v = 0;
    if (key < NN) v = f2bf(ab[h * n_off + bidx[q * NN + key]]);
    biasB[(size_t)h * NN2 * KPAD + i] = v;
}

// ---------------- MFMA attention v6b: distance-2 prefetch (bias snapshot fix) + setprio ----------------
__global__ __launch_bounds__(256)
void attn_mfma6_kernel(const short* __restrict__ QT, const short* __restrict__ KT,
                       const short* __restrict__ V, const short* __restrict__ biasB,
                       float* __restrict__ outT) {
    __shared__ __align__(16) char Ps[4][2048];

    const int t = threadIdx.x;
    const int bid = blockIdx.x;           // head <-> XCD, qt innermost
    const int h  = bid & 7;
    const int qt = (bid >> 3) & 3;
    const int b  = bid >> 5;

    const int lane = t & 63, wid = t >> 6;
    const int lr = lane & 15, kg = lane >> 4;
    const int qg = qt * 64 + wid * 16 + lr;
    const int qsafe = (qg < NN2) ? qg : (NN2 - 1);

    const short* qrow = QT + ((size_t)(b * 8 + h) * QPAD + qg) * 32;
    bf16x8 qb1 = *(const bf16x8*)(qrow + (kg & 1) * 8);           // [Qhi|Qhi] (pre-scaled by 0.25)
    bf16x8 qb2 = (bf16x8){0, 0, 0, 0, 0, 0, 0, 0};                // [Qlo|0]
    if (kg < 2) qb2 = *(const bf16x8*)(qrow + 16 + kg * 8);

    const short* kbase = KT + (size_t)(b * 8 + h) * KPAD * 32;
    const short* vbase = V + ((size_t)b * DH + h * DD) * KPAD;
    const short* bbase = biasB + ((size_t)h * NN2 + qsafe) * KPAD;

    f32x4 acc[4];
    #pragma unroll
    for (int n = 0; n < 4; ++n) acc[n] = (f32x4){0.f, 0.f, 0.f, 0.f};
    float sacc = 0.f;
    char* Psw = &Ps[wid][0];
    const int swz = (lr & 7) << 4;

    bf16x8 kaA[4], kaB[4];
    short4 b4A[4], b4B[4];

    auto LOADKB = [&](int tile, bf16x8* ka, short4* b4) {
        int k0 = tile * 64;
        #pragma unroll
        for (int nt = 0; nt < 4; ++nt) {
            ka[nt] = *(const bf16x8*)(kbase + (size_t)(k0 + nt * 16 + lr) * 32 + kg * 8);
            b4[nt] = *(const short4*)(bbase + k0 + nt * 16 + kg * 4);
        }
    };

    auto COMPUTE = [&](int tile, bf16x8* ka, short4* b4) {
        const int k0 = tile * 64;
        // snapshot current tile's bias BEFORE prefetch overwrites b4 (R8 bug fix)
        short4 cb[4];
        #pragma unroll
        for (int nt = 0; nt < 4; ++nt) cb[nt] = b4[nt];
        // issue all V loads up front (latency hidden by QK+softmax)
        bf16x8 vf[8];
        #pragma unroll
        for (int ks = 0; ks < 2; ++ks)
            #pragma unroll
            for (int nt = 0; nt < 4; ++nt)
                vf[ks * 4 + nt] = *(const bf16x8*)(vbase + (size_t)(nt * 16 + lr) * KPAD
                                                   + k0 + ks * 32 + kg * 8);
        // QK^T
        f32x4 sc[4];
        __builtin_amdgcn_s_setprio(1);
        #pragma unroll
        for (int nt = 0; nt < 4; ++nt) {
            sc[nt] = (f32x4){0.f, 0.f, 0.f, 0.f};
            sc[nt] = MFMA32(ka[nt], qb1, sc[nt]);
            sc[nt] = MFMA32(ka[nt], qb2, sc[nt]);
        }
        __builtin_amdgcn_s_setprio(0);

        // prefetch tile+2's K/bias into the buffers QK just freed
        if (tile + 2 <= 12) LOADKB(tile + 2, ka, b4);

        // softmax-numerator + pack (uses snapshot cb)
        #pragma unroll
        for (int nt = 0; nt < 4; ++nt) {
            int keyb = k0 + nt * 16 + kg * 4;
            bool kvalid = keyb < NN;
            short4 pk;
            #pragma unroll
            for (int r = 0; r < 4; ++r) {
                float sv = sc[nt][r] + bf2f(((const short*)&cb[nt])[r]);
                float pv = kvalid ? __expf(sv) : 0.f;
                sacc += pv;
                ((short*)&pk)[r] = f2bf(pv);
            }
            *(short4*)(Psw + lr * 128 + ((nt * 32 + kg * 8) ^ swz)) = pk;
        }
        // PV
        #pragma unroll
        for (int ks = 0; ks < 2; ++ks) {
            bf16x8 pa = *(const bf16x8*)(Psw + lr * 128 + ((ks * 64 + kg * 16) ^ swz));
            __builtin_amdgcn_s_setprio(1);
            #pragma unroll
            for (int nt = 0; nt < 4; ++nt)
                acc[nt] = MFMA32(pa, vf[ks * 4 + nt], acc[nt]);
            __builtin_amdgcn_s_setprio(0);
        }
    };

    LOADKB(0, kaA, b4A);
    LOADKB(1, kaB, b4B);
    #pragma unroll 1
    for (int tile = 0; tile < 12; tile += 2) {
        COMPUTE(tile,     kaA, b4A);   // prefetches tile+2 into A
        COMPUTE(tile + 1, kaB, b4B);   // prefetches tile+3 into B
    }
    COMPUTE(12, kaA, b4A);

    sacc += __shfl_xor(sacc, 16, 64);
    sacc += __shfl_xor(sacc, 32, 64);

    #pragma unroll
    for (int r = 0; r < 4; ++r) {
        int qrow_ = qt * 64 + wid * 16 + kg * 4 + r;
        if (qrow_ >= NN2) continue;
        float inv = 1.f / __shfl(sacc, kg * 4 + r, 64);
        #pragma unroll
        for (int nt = 0; nt < 4; ++nt) {
            int d = nt * 16 + lr;
            outT[((size_t)b * NN2 + qrow_) * DH + h * DD + d] = acc[nt][r] * inv;
        }
    }
}

// ---------------- gelu(attnT + vlocal^T) -> gT hi/lo [b][256][512] ----------------
__global__ void gelu_addT_kernel(const float* __restrict__ aT, const float* __restrict__ vloc,
                                 short* __restrict__ g_hi, short* __restrict__ g_lo) {
    __shared__ float tile[32][33];
    int ntb = blockIdx.x * 32, ctb = blockIdx.y * 32, b = blockIdx.z;
    int tn = threadIdx.x & 31, tc4 = threadIdx.x >> 5;
    #pragma unroll
    for (int i = 0; i < 4; ++i) {
        int c = tc4 + i * 8;
        int n = ntb + tn;
        tile[c][tn] = (n < NN2) ? vloc[((size_t)b * DH + ctb + c) * NN2 + n] : 0.f;
    }
    __syncthreads();
    int tc = threadIdx.x & 31, tn4 = threadIdx.x >> 5;
    #pragma unroll
    for (int i = 0; i < 4; ++i) {
        int n = ntb + tn4 + i * 8;
        float g = 0.f;
        if (n < NN2) {
            float sum = aT[((size_t)b * NN2 + n) * DH + ctb + tc] + tile[tc][tn4 + i * 8];
            g = 0.5f * sum * (1.f + erff(sum * 0.70710678118654752440f));
        }
        short hh = f2bf(g);
        size_t o = ((size_t)b * QPAD + n) * DH + ctb + tc;
        g_hi[o] = hh;
        g_lo[o] = f2bf(g - bf2f(hh));
    }
}

extern "C" void kernel_launch(void* const* d_in, const int* in_sizes, int n_in,
                              void* d_out, int out_size, void* d_ws, size_t ws_size,
                              hipStream_t stream) {
    const float* x     = (const float*)d_in[0];
    const float* ql_w  = (const float*)d_in[1];
    const float* ql_b  = (const float*)d_in[2];
    const float* qp_w  = (const float*)d_in[3];
    const float* qp_b  = (const float*)d_in[4];
    const float* qp_s  = (const float*)d_in[5];
    const float* qp_o  = (const float*)d_in[6];
    const float* k_w   = (const float*)d_in[7];
    const float* k_b   = (const float*)d_in[8];
    const float* k_s   = (const float*)d_in[9];
    const float* k_o   = (const float*)d_in[10];
    const float* v_w   = (const float*)d_in[11];
    const float* v_b   = (const float*)d_in[12];
    const float* v_s   = (const float*)d_in[13];
    const float* v_o   = (const float*)d_in[14];
    const float* vl_w  = (const float*)d_in[15];
    const float* vl_b  = (const float*)d_in[16];
    const float* vl_s  = (const float*)d_in[17];
    const float* vl_o  = (const float*)d_in[18];
    const float* p_w   = (const float*)d_in[19];
    const float* p_b   = (const float*)d_in[20];
    const float* p_s   = (const float*)d_in[21];
    const float* p_o   = (const float*)d_in[22];
    const float* ab    = (const float*)d_in[23];
    const int*   bidx  = (const int*)d_in[24];
    float* out = (float*)d_out;
    int n_off = in_sizes[23] / HEADS;

    char* ws = (char*)d_ws;
    short* qinT_h = (short*)(ws + O_QINT_HI);
    short* xT_h   = (short*)(ws + O_XT_HI);
    short* QT     = (short*)(ws + O_QT);
    short* KT     = (short*)(ws + O_KT);
    short* Vb     = (short*)(ws + O_V);
    float* vlocal = (float*)(ws + O_VLOCAL);
    short* biasB  = (short*)(ws + O_BIASB);
    short* w_h    = (short*)(ws + O_W_HI);
    short* w_l    = (short*)(ws + O_W_LO);
    float* attnT  = (float*)(ws + O_ATTNT);
    short* gT_h   = (short*)(ws + O_GT_HI);
    short* gT_l   = (short*)(ws + O_GT_LO);

    // 1. qin fused: dwconv+pool -> transposed bf16 [b][256][384]
    qinT_kernel<<<dim3(DIMC, BATCH), 256, 0, stream>>>(x, ql_w, ql_b, qinT_h);
    // 2. weight splits
    wsplit_kernel<<<dim3(1920), 256, 0, stream>>>(qp_w, k_w, v_w, p_w, w_h, w_l);
    // 3. q projection -> QT packed (pre-scaled by SCALE)
    gemm_split_kernel<false><<<dim3(2, 1, BATCH), 256, 0, stream>>>(
        w_h + 0, w_l + 0, qinT_h, nullptr, qp_b, qp_s, qp_o,
        nullptr, QT, 2, DIMC, NN2, QPAD, QPAD, SCALE);
    // 4. x -> xT (bf16)
    tsplit_kernel<<<dim3(XPAD / 32, DIMC / 32, BATCH), 256, 0, stream>>>(x, xT_h, DIMC, NN, XPAD);
    // 5. k projection -> KT packed
    gemm_split_kernel<false><<<dim3(7, 1, BATCH), 256, 0, stream>>>(
        w_h + 49152, w_l + 49152, xT_h, nullptr, k_b, k_s, k_o,
        nullptr, KT, 2, DIMC, NN, XPAD, KPAD, 1.0f);
    // 6. v projection -> bf16 [b][512][832]
    gemm_split_kernel<false><<<dim3(7, 4, BATCH), 256, 0, stream>>>(
        w_h + 98304, w_l + 98304, xT_h, nullptr, v_b, v_s, v_o,
        nullptr, Vb, 1, DIMC, NN, XPAD, KPAD, 1.0f);
    // 7. v_local
    vlocal_kernel<<<dim3(DH, BATCH), 256, 0, stream>>>(Vb, vl_w, vl_b, vl_s, vl_o, vlocal);
    // 8. bias expand
    biasB_expand_kernel<<<dim3((NN2 * KPAD + 255) / 256, HEADS), 256, 0, stream>>>(ab, bidx, biasB, n_off);
    // 9. attention
    attn_mfma6_kernel<<<dim3(4 * HEADS * BATCH), 256, 0, stream>>>(QT, KT, Vb, biasB, attnT);
    // 10. gelu
    gelu_addT_kernel<<<dim3(QPAD / 32, DH / 32, BATCH), 256, 0, stream>>>(attnT, vlocal, gT_h, gT_l);
    // 11. output projection
    gemm_split_kernel<true><<<dim3(2, 3, BATCH), 256, 0, stream>>>(
        w_h + 294912, w_l + 294912, gT_h, gT_l, p_b, p_s, p_o,
        out, nullptr, 0, DH, NN2, QPAD, 0, 1.0f);
}

// Round 10
// 428.027 us; speedup vs baseline: 1.1822x; 1.1822x over previous
//
#include <hip/hip_runtime.h>
#include <math.h>

#define BATCH   64
#define DIMC    384
#define KEY_DIM 16
#define HEADS   8
#define DD      64
#define DH      512
#define NH_KD   128
#define RES     28
#define RES2    14
#define NN      784
#define NN2     196
#define OUT_DIM 384
#define SCALE   0.25f
#define XPAD    896     // 7*128
#define QPAD    256     // 2*128
#define KPAD    832     // 13*64

typedef __attribute__((ext_vector_type(8))) short bf16x8;
typedef __attribute__((ext_vector_type(4))) float f32x4;

#define MFMA32(a, b, c) __builtin_amdgcn_mfma_f32_16x16x32_bf16(a, b, c, 0, 0, 0)

__device__ inline short f2bf(float f) {
    unsigned u = __float_as_uint(f);
    unsigned r = (u + 0x7fff + ((u >> 16) & 1)) >> 16;
    return (short)r;
}
__device__ inline float bf2f(short h) {
    return __uint_as_float(((unsigned)(unsigned short)h) << 16);
}

// ---- ws byte offsets ----
#define O_QINT_HI  20971520u    // bf16 qinT [b][256][384] (step 1 -> 3)
#define O_XT_HI    0u           // bf16 xT [b][896][384] (step 4 -> 6)
#define O_QT       88080384u    // packed QT (step 3 -> 9)
#define O_KT       96468992u    // packed KT (step 5 -> 9)
#define O_V        123731968u   // bf16 V [b][512][832] (step 6 -> 9)
#define O_VLOCAL   178257920u   // fp32 (step 7 -> 10)
#define O_BIASB    203948032u   // bf16 (step 8 -> 9)
#define O_W_HI     206557184u
#define O_W_LO     207540224u
#define O_ATTNT    0u           // fp32 (step 9 -> 10; xT dead)
#define O_GT_HI    25690112u    // (step 10 -> 11)
#define O_GT_LO    42467328u

// ---------------- qinT = f2bf(dwconv3x3 s2 (pad 1) + pool), transposed [b][QPAD][C] ----------------
__global__ void qinT_kernel(const float* __restrict__ x, const float* __restrict__ ql_w,
                            const float* __restrict__ ql_b, short* __restrict__ qinT) {
    int c = blockIdx.x, b = blockIdx.y, n2 = threadIdx.x;
    if (n2 >= NN2) return;
    int i = n2 / RES2, j = n2 % RES2;
    const float* xp = x + ((size_t)b * DIMC + c) * (RES * RES);
    const float* w  = ql_w + c * 9;
    float acc = ql_b[c];
    #pragma unroll
    for (int di = 0; di < 3; ++di) {
        int r = 2 * i + di - 1;
        if (r < 0 || r >= RES) continue;
        #pragma unroll
        for (int dj = 0; dj < 3; ++dj) {
            int cc = 2 * j + dj - 1;
            if (cc < 0 || cc >= RES) continue;
            acc += xp[r * RES + cc] * w[di * 3 + dj];
        }
    }
    acc += xp[(2 * i) * RES + 2 * j];
    qinT[((size_t)b * QPAD + n2) * DIMC + c] = f2bf(acc);
}

// ---------------- weight split ----------------
__global__ void wsplit_kernel(const float* __restrict__ w0, const float* __restrict__ w1,
                              const float* __restrict__ w2, const float* __restrict__ w3,
                              short* __restrict__ hi, short* __restrict__ lo) {
    int i = blockIdx.x * 256 + threadIdx.x;
    if (i >= 491520) return;
    const float* src; int j = i;
    if (j < 49152) src = w0;
    else if (j < 98304) { src = w1; j -= 49152; }
    else if (j < 294912) { src = w2; j -= 98304; }
    else { src = w3; j -= 294912; }
    float v = src[j];
    short h = f2bf(v);
    hi[i] = h;
    lo[i] = f2bf(v - bf2f(h));
}

// ---------------- transpose + bf16: [b][C][N] f32 -> [b][Npad][C] bf16 ----------------
__global__ void tsplit_kernel(const float* __restrict__ in, short* __restrict__ out_hi,
                              int C, int N, int Npad) {
    __shared__ float tile[32][33];
    int ntb = blockIdx.x * 32, ctb = blockIdx.y * 32, b = blockIdx.z;
    int tn = threadIdx.x & 31, tc4 = threadIdx.x >> 5;
    #pragma unroll
    for (int i = 0; i < 4; ++i) {
        int c = tc4 + i * 8;
        int n = ntb + tn;
        tile[c][tn] = (n < N) ? in[((size_t)b * C + ctb + c) * N + n] : 0.f;
    }
    __syncthreads();
    int tc = threadIdx.x & 31, tn4 = threadIdx.x >> 5;
    #pragma unroll
    for (int i = 0; i < 4; ++i) {
        int n = tn4 + i * 8;
        out_hi[((size_t)b * Npad + ntb + n) * C + ctb + tc] = f2bf(tile[tc][n]);
    }
}

// ---------------- split-bf16 MFMA GEMM ----------------
// A = weights hi/lo; B = activations hi (+lo if BLO)
// mode 0: fp32 [b][O][Nn]; mode 1: bf16 [b][O][NPADo] zero-padded;
// mode 2: packed [b*8+h][NPADo][16hi|16lo] (O=128), value scaled by pscale
template<bool BLO>
__global__ __launch_bounds__(256)
void gemm_split_kernel(const short* __restrict__ Ag_hi, const short* __restrict__ Ag_lo,
                       const short* __restrict__ Bg_hi, const short* __restrict__ Bg_lo,
                       const float* __restrict__ bias, const float* __restrict__ s,
                       const float* __restrict__ off,
                       float* __restrict__ out_f, short* __restrict__ out_b,
                       int mode, int C, int Nn, int Npad, int NPADo, float pscale) {
    __shared__ __align__(16) short Ah[128 * 32], Al[128 * 32], Bh[128 * 32];
    __shared__ __align__(16) short Bl[BLO ? 128 * 32 : 64];

    const int t = threadIdx.x;
    const int n0 = blockIdx.x * 128, o0 = blockIdx.y * 128, b = blockIdx.z;
    const int O = gridDim.y * 128;
    const int lane = t & 63, wid = t >> 6;
    const int wm = wid & 1, wn = wid >> 1;
    const int lr = lane & 15, kg = lane >> 4;

    f32x4 acc[4][4];
    #pragma unroll
    for (int m = 0; m < 4; ++m)
        #pragma unroll
        for (int n = 0; n < 4; ++n)
            acc[m][n] = (f32x4){0.f, 0.f, 0.f, 0.f};

    const int srow = t >> 2;
    const int sch  = (t & 3) * 8;
    const size_t aBase = (size_t)(o0 + srow) * C + sch;
    const size_t bBase = ((size_t)b * Npad + n0 + srow) * C + sch;
    const size_t rstep = (size_t)64 * C;

    bf16x8 rA[2], rAl[2], rB[2], rBl[2];
    #pragma unroll
    for (int p = 0; p < 2; ++p) {
        rA[p]  = *(const bf16x8*)(Ag_hi + aBase + p * rstep);
        rAl[p] = *(const bf16x8*)(Ag_lo + aBase + p * rstep);
        rB[p]  = *(const bf16x8*)(Bg_hi + bBase + p * rstep);
        if constexpr (BLO) rBl[p] = *(const bf16x8*)(Bg_lo + bBase + p * rstep);
    }

    for (int k0 = 0;; k0 += 32) {
        #pragma unroll
        for (int p = 0; p < 2; ++p) {
            int la = (srow + p * 64) * 32 + sch;
            *(bf16x8*)&Ah[la] = rA[p];
            *(bf16x8*)&Al[la] = rAl[p];
            *(bf16x8*)&Bh[la] = rB[p];
            if constexpr (BLO) *(bf16x8*)&Bl[la] = rBl[p];
        }
        __syncthreads();

        if (k0 + 32 < C) {
            #pragma unroll
            for (int p = 0; p < 2; ++p) {
                rA[p]  = *(const bf16x8*)(Ag_hi + aBase + (k0 + 32) + p * rstep);
                rAl[p] = *(const bf16x8*)(Ag_lo + aBase + (k0 + 32) + p * rstep);
                rB[p]  = *(const bf16x8*)(Bg_hi + bBase + (k0 + 32) + p * rstep);
                if constexpr (BLO) rBl[p] = *(const bf16x8*)(Bg_lo + bBase + (k0 + 32) + p * rstep);
            }
        }

        bf16x8 ah[4], al[4];
        #pragma unroll
        for (int m = 0; m < 4; ++m) {
            int row = wm * 64 + m * 16 + lr;
            ah[m] = *(const bf16x8*)&Ah[row * 32 + kg * 8];
            al[m] = *(const bf16x8*)&Al[row * 32 + kg * 8];
        }
        #pragma unroll
        for (int nf = 0; nf < 4; ++nf) {
            int row = wn * 64 + nf * 16 + lr;
            bf16x8 bh = *(const bf16x8*)&Bh[row * 32 + kg * 8];
            #pragma unroll
            for (int m = 0; m < 4; ++m) {
                acc[m][nf] = MFMA32(ah[m], bh, acc[m][nf]);
                acc[m][nf] = MFMA32(al[m], bh, acc[m][nf]);
            }
            if constexpr (BLO) {
                bf16x8 bl = *(const bf16x8*)&Bl[row * 32 + kg * 8];
                #pragma unroll
                for (int m = 0; m < 4; ++m)
                    acc[m][nf] = MFMA32(ah[m], bl, acc[m][nf]);
            }
        }
        if (k0 + 32 >= C) break;
        __syncthreads();
    }

    #pragma unroll
    for (int m = 0; m < 4; ++m) {
        #pragma unroll
        for (int nf = 0; nf < 4; ++nf) {
            int col = n0 + wn * 64 + nf * 16 + lr;
            if (mode == 0) {
                if (col >= Nn) continue;
                #pragma unroll
                for (int r = 0; r < 4; ++r) {
                    int row = o0 + wm * 64 + m * 16 + kg * 4 + r;
                    float a = s[row];
                    out_f[((size_t)b * O + row) * Nn + col] =
                        acc[m][nf][r] * a + (bias[row] * a + off[row]);
                }
            } else if (mode == 1) {
                if (col >= NPADo) continue;
                #pragma unroll
                for (int r = 0; r < 4; ++r) {
                    int row = o0 + wm * 64 + m * 16 + kg * 4 + r;
                    short hv = 0;
                    if (col < Nn) {
                        float a = s[row];
                        hv = f2bf(acc[m][nf][r] * a + (bias[row] * a + off[row]));
                    }
                    out_b[((size_t)b * O + row) * NPADo + col] = hv;
                }
            } else {
                if (col >= NPADo) continue;
                int hh = (o0 + wm * 64 + m * 16) >> 4;
                short4 h4, l4;
                #pragma unroll
                for (int r = 0; r < 4; ++r) {
                    int row = o0 + wm * 64 + m * 16 + kg * 4 + r;
                    float v = 0.f;
                    if (col < Nn) {
                        float a = s[row];
                        v = (acc[m][nf][r] * a + (bias[row] * a + off[row])) * pscale;
                    }
                    short hv = f2bf(v);
                    ((short*)&h4)[r] = hv;
                    ((short*)&l4)[r] = f2bf(v - bf2f(hv));
                }
                size_t base = ((size_t)(b * 8 + hh) * NPADo + col) * 32 + kg * 4;
                *(short4*)(out_b + base)      = h4;
                *(short4*)(out_b + base + 16) = l4;
            }
        }
    }
}

// ---------------- v_local ----------------
__global__ void vlocal_kernel(const short* __restrict__ v,
                              const float* __restrict__ vl_w, const float* __restrict__ vl_b,
                              const float* __restrict__ vl_s, const float* __restrict__ vl_o,
                              float* __restrict__ vlocal) {
    int c = blockIdx.x, b = blockIdx.y, n2 = threadIdx.x;
    if (n2 >= NN2) return;
    int i = n2 / RES2, j = n2 % RES2;
    const size_t base = ((size_t)b * DH + c) * KPAD;
    const float* w = vl_w + c * 9;
    float acc = vl_b[c];
    #pragma unroll
    for (int di = 0; di < 3; ++di) {
        int r = 2 * i + di - 1;
        if (r < 0 || r >= RES) continue;
        #pragma unroll
        for (int dj = 0; dj < 3; ++dj) {
            int cc = 2 * j + dj - 1;
            if (cc < 0 || cc >= RES) continue;
            acc += bf2f(v[base + r * RES + cc]) * w[di * 3 + dj];
        }
    }
    vlocal[((size_t)b * DH + c) * NN2 + n2] = acc * vl_s[c] + vl_o[c];
}

// ---------------- bias expand -> bf16, padded rows of 832 ----------------
__global__ void biasB_expand_kernel(const float* __restrict__ ab, const int* __restrict__ bidx,
                                    short* __restrict__ biasB, int n_off) {
    int i = blockIdx.x * 256 + threadIdx.x;
    int h = blockIdx.y;
    if (i >= NN2 * KPAD) return;
    int q = i / KPAD, key = i - q * KPAD;
    short v = 0;
    if (key < NN) v = f2bf(ab[h * n_off + bidx[q * NN + key]]);
    biasB[(size_t)h * NN2 * KPAD + i] = v;
}

// ---------------- MFMA attention v7: 64 queries/wave, 1 block per (b,h) ----------------
// 4x arithmetic intensity per VMEM vs v6; K dist-2 double-buffer; zero barriers.
__global__ __launch_bounds__(256)
void attn_mfma7_kernel(const short* __restrict__ QT, const short* __restrict__ KT,
                       const short* __restrict__ V, const short* __restrict__ biasB,
                       float* __restrict__ outT) {
    __shared__ __align__(16) char Ps[4][4][2048];   // [wave][qf][16 q x 128B keys]

    const int t = threadIdx.x;
    const int bid = blockIdx.x;           // 512 blocks: head <-> XCD
    const int h = bid & 7;
    const int b = bid >> 3;

    const int lane = t & 63, wid = t >> 6;
    const int lr = lane & 15, kg = lane >> 4;
    const int wq0 = wid * 64;             // this wave's query base (64 queries)

    // Q fragments for 4 q-subtiles (pre-scaled by SCALE at pack time)
    bf16x8 qb1[4], qb2[4];
    #pragma unroll
    for (int qf = 0; qf < 4; ++qf) {
        int qg = wq0 + qf * 16 + lr;
        const short* qrow = QT + ((size_t)(b * 8 + h) * QPAD + qg) * 32;
        qb1[qf] = *(const bf16x8*)(qrow + (kg & 1) * 8);          // [Qhi|Qhi]
        qb2[qf] = (bf16x8){0, 0, 0, 0, 0, 0, 0, 0};               // [Qlo|0]
        if (kg < 2) qb2[qf] = *(const bf16x8*)(qrow + 16 + kg * 8);
    }

    const short* kbase = KT + (size_t)(b * 8 + h) * KPAD * 32;
    const short* vbase = V + ((size_t)b * DH + h * DD) * KPAD;
    const short* bb[4];
    #pragma unroll
    for (int qf = 0; qf < 4; ++qf) {
        int qg = wq0 + qf * 16 + lr;
        int qs = (qg < NN2) ? qg : (NN2 - 1);
        bb[qf] = biasB + ((size_t)h * NN2 + qs) * KPAD;
    }

    f32x4 acc[4][4];    // [qf][nt]
    #pragma unroll
    for (int qf = 0; qf < 4; ++qf)
        #pragma unroll
        for (int nt = 0; nt < 4; ++nt)
            acc[qf][nt] = (f32x4){0.f, 0.f, 0.f, 0.f};
    float sacc[4] = {0.f, 0.f, 0.f, 0.f};
    char* PsBase = &Ps[wid][0][0];
    const int swz = (lr & 7) << 4;

    bf16x8 kaA[4], kaB[4];

    auto LOADK = [&](int tile, bf16x8* ka) {
        int k0 = tile * 64;
        #pragma unroll
        for (int nt = 0; nt < 4; ++nt)
            ka[nt] = *(const bf16x8*)(kbase + (size_t)(k0 + nt * 16 + lr) * 32 + kg * 8);
    };

    auto COMPUTE = [&](int tile, bf16x8* ka) {
        const int k0 = tile * 64;
        // V fragments (shared across all 4 qf)
        bf16x8 vf[8];
        #pragma unroll
        for (int ks = 0; ks < 2; ++ks)
            #pragma unroll
            for (int nt = 0; nt < 4; ++nt)
                vf[ks * 4 + nt] = *(const bf16x8*)(vbase + (size_t)(nt * 16 + lr) * KPAD
                                                   + k0 + ks * 32 + kg * 8);
        // bias for all qf (issued early; hidden under QK MFMA bursts)
        short4 b4[4][4];
        #pragma unroll
        for (int qf = 0; qf < 4; ++qf)
            #pragma unroll
            for (int nt = 0; nt < 4; ++nt)
                b4[qf][nt] = *(const short4*)(bb[qf] + k0 + nt * 16 + kg * 4);

        #pragma unroll
        for (int qf = 0; qf < 4; ++qf) {
            // QK^T for this q-subtile
            f32x4 sc[4];
            __builtin_amdgcn_s_setprio(1);
            #pragma unroll
            for (int nt = 0; nt < 4; ++nt) {
                sc[nt] = (f32x4){0.f, 0.f, 0.f, 0.f};
                sc[nt] = MFMA32(ka[nt], qb1[qf], sc[nt]);
                sc[nt] = MFMA32(ka[nt], qb2[qf], sc[nt]);
            }
            __builtin_amdgcn_s_setprio(0);

            // after the last QK consumer, prefetch tile+2's K into this buffer
            if (qf == 3 && tile + 2 <= 12) LOADK(tile + 2, ka);

            // softmax numerator + pack
            char* Psw = PsBase + qf * 2048;
            #pragma unroll
            for (int nt = 0; nt < 4; ++nt) {
                int keyb = k0 + nt * 16 + kg * 4;
                bool kvalid = keyb < NN;
                short4 pk;
                #pragma unroll
                for (int r = 0; r < 4; ++r) {
                    float sv = sc[nt][r] + bf2f(((const short*)&b4[qf][nt])[r]);
                    float pv = kvalid ? __expf(sv) : 0.f;
                    sacc[qf] += pv;
                    ((short*)&pk)[r] = f2bf(pv);
                }
                *(short4*)(Psw + lr * 128 + ((nt * 32 + kg * 8) ^ swz)) = pk;
            }
            // PV for this q-subtile (V frags reused across qf)
            #pragma unroll
            for (int ks = 0; ks < 2; ++ks) {
                bf16x8 pa = *(const bf16x8*)(Psw + lr * 128 + ((ks * 64 + kg * 16) ^ swz));
                __builtin_amdgcn_s_setprio(1);
                #pragma unroll
                for (int nt = 0; nt < 4; ++nt)
                    acc[qf][nt] = MFMA32(pa, vf[ks * 4 + nt], acc[qf][nt]);
                __builtin_amdgcn_s_setprio(0);
            }
        }
    };

    LOADK(0, kaA);
    LOADK(1, kaB);
    #pragma unroll 1
    for (int tile = 0; tile < 12; tile += 2) {
        COMPUTE(tile,     kaA);   // prefetches tile+2 into A
        COMPUTE(tile + 1, kaB);   // prefetches tile+3 into B
    }
    COMPUTE(12, kaA);

    #pragma unroll
    for (int qf = 0; qf < 4; ++qf) {
        float sv = sacc[qf];
        sv += __shfl_xor(sv, 16, 64);
        sv += __shfl_xor(sv, 32, 64);
        #pragma unroll
        for (int r = 0; r < 4; ++r) {
            int qrow_ = wq0 + qf * 16 + kg * 4 + r;
            if (qrow_ >= NN2) continue;
            float inv = 1.f / __shfl(sv, kg * 4 + r, 64);
            #pragma unroll
            for (int nt = 0; nt < 4; ++nt) {
                int d = nt * 16 + lr;
                outT[((size_t)b * NN2 + qrow_) * DH + h * DD + d] = acc[qf][nt][r] * inv;
            }
        }
    }
}

// ---------------- gelu(attnT + vlocal^T) -> gT hi/lo [b][256][512] ----------------
__global__ void gelu_addT_kernel(const float* __restrict__ aT, const float* __restrict__ vloc,
                                 short* __restrict__ g_hi, short* __restrict__ g_lo) {
    __shared__ float tile[32][33];
    int ntb = blockIdx.x * 32, ctb = blockIdx.y * 32, b = blockIdx.z;
    int tn = threadIdx.x & 31, tc4 = threadIdx.x >> 5;
    #pragma unroll
    for (int i = 0; i < 4; ++i) {
        int c = tc4 + i * 8;
        int n = ntb + tn;
        tile[c][tn] = (n < NN2) ? vloc[((size_t)b * DH + ctb + c) * NN2 + n] : 0.f;
    }
    __syncthreads();
    int tc = threadIdx.x & 31, tn4 = threadIdx.x >> 5;
    #pragma unroll
    for (int i = 0; i < 4; ++i) {
        int n = ntb + tn4 + i * 8;
        float g = 0.f;
        if (n < NN2) {
            float sum = aT[((size_t)b * NN2 + n) * DH + ctb + tc] + tile[tc][tn4 + i * 8];
            g = 0.5f * sum * (1.f + erff(sum * 0.70710678118654752440f));
        }
        short hh = f2bf(g);
        size_t o = ((size_t)b * QPAD + n) * DH + ctb + tc;
        g_hi[o] = hh;
        g_lo[o] = f2bf(g - bf2f(hh));
    }
}

extern "C" void kernel_launch(void* const* d_in, const int* in_sizes, int n_in,
                              void* d_out, int out_size, void* d_ws, size_t ws_size,
                              hipStream_t stream) {
    const float* x     = (const float*)d_in[0];
    const float* ql_w  = (const float*)d_in[1];
    const float* ql_b  = (const float*)d_in[2];
    const float* qp_w  = (const float*)d_in[3];
    const float* qp_b  = (const float*)d_in[4];
    const float* qp_s  = (const float*)d_in[5];
    const float* qp_o  = (const float*)d_in[6];
    const float* k_w   = (const float*)d_in[7];
    const float* k_b   = (const float*)d_in[8];
    const float* k_s   = (const float*)d_in[9];
    const float* k_o   = (const float*)d_in[10];
    const float* v_w   = (const float*)d_in[11];
    const float* v_b   = (const float*)d_in[12];
    const float* v_s   = (const float*)d_in[13];
    const float* v_o   = (const float*)d_in[14];
    const float* vl_w  = (const float*)d_in[15];
    const float* vl_b  = (const float*)d_in[16];
    const float* vl_s  = (const float*)d_in[17];
    const float* vl_o  = (const float*)d_in[18];
    const float* p_w   = (const float*)d_in[19];
    const float* p_b   = (const float*)d_in[20];
    const float* p_s   = (const float*)d_in[21];
    const float* p_o   = (const float*)d_in[22];
    const float* ab    = (const float*)d_in[23];
    const int*   bidx  = (const int*)d_in[24];
    float* out = (float*)d_out;
    int n_off = in_sizes[23] / HEADS;

    char* ws = (char*)d_ws;
    short* qinT_h = (short*)(ws + O_QINT_HI);
    short* xT_h   = (short*)(ws + O_XT_HI);
    short* QT     = (short*)(ws + O_QT);
    short* KT     = (short*)(ws + O_KT);
    short* Vb     = (short*)(ws + O_V);
    float* vlocal = (float*)(ws + O_VLOCAL);
    short* biasB  = (short*)(ws + O_BIASB);
    short* w_h    = (short*)(ws + O_W_HI);
    short* w_l    = (short*)(ws + O_W_LO);
    float* attnT  = (float*)(ws + O_ATTNT);
    short* gT_h   = (short*)(ws + O_GT_HI);
    short* gT_l   = (short*)(ws + O_GT_LO);

    // 1. qin fused: dwconv+pool -> transposed bf16 [b][256][384]
    qinT_kernel<<<dim3(DIMC, BATCH), 256, 0, stream>>>(x, ql_w, ql_b, qinT_h);
    // 2. weight splits
    wsplit_kernel<<<dim3(1920), 256, 0, stream>>>(qp_w, k_w, v_w, p_w, w_h, w_l);
    // 3. q projection -> QT packed (pre-scaled by SCALE)
    gemm_split_kernel<false><<<dim3(2, 1, BATCH), 256, 0, stream>>>(
        w_h + 0, w_l + 0, qinT_h, nullptr, qp_b, qp_s, qp_o,
        nullptr, QT, 2, DIMC, NN2, QPAD, QPAD, SCALE);
    // 4. x -> xT (bf16)
    tsplit_kernel<<<dim3(XPAD / 32, DIMC / 32, BATCH), 256, 0, stream>>>(x, xT_h, DIMC, NN, XPAD);
    // 5. k projection -> KT packed
    gemm_split_kernel<false><<<dim3(7, 1, BATCH), 256, 0, stream>>>(
        w_h + 49152, w_l + 49152, xT_h, nullptr, k_b, k_s, k_o,
        nullptr, KT, 2, DIMC, NN, XPAD, KPAD, 1.0f);
    // 6. v projection -> bf16 [b][512][832]
    gemm_split_kernel<false><<<dim3(7, 4, BATCH), 256, 0, stream>>>(
        w_h + 98304, w_l + 98304, xT_h, nullptr, v_b, v_s, v_o,
        nullptr, Vb, 1, DIMC, NN, XPAD, KPAD, 1.0f);
    // 7. v_local
    vlocal_kernel<<<dim3(DH, BATCH), 256, 0, stream>>>(Vb, vl_w, vl_b, vl_s, vl_o, vlocal);
    // 8. bias expand
    biasB_expand_kernel<<<dim3((NN2 * KPAD + 255) / 256, HEADS), 256, 0, stream>>>(ab, bidx, biasB, n_off);
    // 9. attention: one block per (b,h), 64 queries/wave
    attn_mfma7_kernel<<<dim3(HEADS * BATCH), 256, 0, stream>>>(QT, KT, Vb, biasB, attnT);
    // 10. gelu
    gelu_addT_kernel<<<dim3(QPAD / 32, DH / 32, BATCH), 256, 0, stream>>>(attnT, vlocal, gT_h, gT_l);
    // 11. output projection
    gemm_split_kernel<true><<<dim3(2, 3, BATCH), 256, 0, stream>>>(
        w_h + 294912, w_l + 294912, gT_h, gT_l, p_b, p_s, p_o,
        out, nullptr, 0, DH, NN2, QPAD, 0, 1.0f);
}

// Round 11
// 401.208 us; speedup vs baseline: 1.2612x; 1.0668x over previous
//
#include <hip/hip_runtime.h>
#include <math.h>

#define BATCH   64
#define DIMC    384
#define KEY_DIM 16
#define HEADS   8
#define DD      64
#define DH      512
#define NH_KD   128
#define RES     28
#define RES2    14
#define NN      784
#define NN2     196
#define OUT_DIM 384
#define SCALE   0.25f
#define XPAD    896     // 7*128
#define QPAD    256     // 2*128
#define KPAD    832     // 13*64

typedef __attribute__((ext_vector_type(8))) short bf16x8;
typedef __attribute__((ext_vector_type(4))) float f32x4;

#define MFMA32(a, b, c) __builtin_amdgcn_mfma_f32_16x16x32_bf16(a, b, c, 0, 0, 0)
// XOR swizzle: spread 64B-stride rows across bank groups (byte offset within tile)
#define SWZ(row, bcol) ((row) * 64 + ((bcol) ^ ((((row) >> 1) & 3) << 4)))

__device__ inline short f2bf(float f) {
    unsigned u = __float_as_uint(f);
    unsigned r = (u + 0x7fff + ((u >> 16) & 1)) >> 16;
    return (short)r;
}
__device__ inline float bf2f(short h) {
    return __uint_as_float(((unsigned)(unsigned short)h) << 16);
}

// ---- ws byte offsets ----
#define O_QINT_HI  20971520u
#define O_XT_HI    0u
#define O_QT       88080384u
#define O_KT       96468992u
#define O_V        123731968u
#define O_VLOCAL   178257920u
#define O_BIASB    203948032u
#define O_W_HI     206557184u
#define O_W_LO     207540224u
#define O_ATTNT    0u
#define O_GT_HI    25690112u
#define O_GT_LO    42467328u

// ---------------- qinT = f2bf(dwconv3x3 s2 (pad 1) + pool), transposed [b][QPAD][C] ----------------
__global__ void qinT_kernel(const float* __restrict__ x, const float* __restrict__ ql_w,
                            const float* __restrict__ ql_b, short* __restrict__ qinT) {
    int c = blockIdx.x, b = blockIdx.y, n2 = threadIdx.x;
    if (n2 >= NN2) return;
    int i = n2 / RES2, j = n2 % RES2;
    const float* xp = x + ((size_t)b * DIMC + c) * (RES * RES);
    const float* w  = ql_w + c * 9;
    float acc = ql_b[c];
    #pragma unroll
    for (int di = 0; di < 3; ++di) {
        int r = 2 * i + di - 1;
        if (r < 0 || r >= RES) continue;
        #pragma unroll
        for (int dj = 0; dj < 3; ++dj) {
            int cc = 2 * j + dj - 1;
            if (cc < 0 || cc >= RES) continue;
            acc += xp[r * RES + cc] * w[di * 3 + dj];
        }
    }
    acc += xp[(2 * i) * RES + 2 * j];
    qinT[((size_t)b * QPAD + n2) * DIMC + c] = f2bf(acc);
}

// ---------------- weight split ----------------
__global__ void wsplit_kernel(const float* __restrict__ w0, const float* __restrict__ w1,
                              const float* __restrict__ w2, const float* __restrict__ w3,
                              short* __restrict__ hi, short* __restrict__ lo) {
    int i = blockIdx.x * 256 + threadIdx.x;
    if (i >= 491520) return;
    const float* src; int j = i;
    if (j < 49152) src = w0;
    else if (j < 98304) { src = w1; j -= 49152; }
    else if (j < 294912) { src = w2; j -= 98304; }
    else { src = w3; j -= 294912; }
    float v = src[j];
    short h = f2bf(v);
    hi[i] = h;
    lo[i] = f2bf(v - bf2f(h));
}

// ---------------- transpose + bf16: [b][C][N] f32 -> [b][Npad][C] bf16 ----------------
__global__ void tsplit_kernel(const float* __restrict__ in, short* __restrict__ out_hi,
                              int C, int N, int Npad) {
    __shared__ float tile[32][33];
    int ntb = blockIdx.x * 32, ctb = blockIdx.y * 32, b = blockIdx.z;
    int tn = threadIdx.x & 31, tc4 = threadIdx.x >> 5;
    #pragma unroll
    for (int i = 0; i < 4; ++i) {
        int c = tc4 + i * 8;
        int n = ntb + tn;
        tile[c][tn] = (n < N) ? in[((size_t)b * C + ctb + c) * N + n] : 0.f;
    }
    __syncthreads();
    int tc = threadIdx.x & 31, tn4 = threadIdx.x >> 5;
    #pragma unroll
    for (int i = 0; i < 4; ++i) {
        int n = tn4 + i * 8;
        out_hi[((size_t)b * Npad + ntb + n) * C + ctb + tc] = f2bf(tile[tc][n]);
    }
}

// ---------------- bf16 MFMA GEMM, swizzled LDS ----------------
// A = weights hi (+lo if ALO); B = activations hi (+lo if BLO)
// mode 0: fp32 [b][O][Nn]; mode 1: bf16 [b][O][NPADo] zero-padded;
// mode 2: packed [b*8+h][NPADo][16hi|16lo] (O=128), scaled by pscale
template<bool ALO, bool BLO>
__global__ __launch_bounds__(256)
void gemm_split_kernel(const short* __restrict__ Ag_hi, const short* __restrict__ Ag_lo,
                       const short* __restrict__ Bg_hi, const short* __restrict__ Bg_lo,
                       const float* __restrict__ bias, const float* __restrict__ s,
                       const float* __restrict__ off,
                       float* __restrict__ out_f, short* __restrict__ out_b,
                       int mode, int C, int Nn, int Npad, int NPADo, float pscale) {
    __shared__ __align__(16) short Ah[128 * 32], Bh[128 * 32];
    __shared__ __align__(16) short Al[ALO ? 128 * 32 : 64];
    __shared__ __align__(16) short Bl[BLO ? 128 * 32 : 64];

    const int t = threadIdx.x;
    const int n0 = blockIdx.x * 128, o0 = blockIdx.y * 128, b = blockIdx.z;
    const int O = gridDim.y * 128;
    const int lane = t & 63, wid = t >> 6;
    const int wm = wid & 1, wn = wid >> 1;
    const int lr = lane & 15, kg = lane >> 4;

    f32x4 acc[4][4];
    #pragma unroll
    for (int m = 0; m < 4; ++m)
        #pragma unroll
        for (int n = 0; n < 4; ++n)
            acc[m][n] = (f32x4){0.f, 0.f, 0.f, 0.f};

    const int srow = t >> 2;
    const int sbc  = (t & 3) * 16;              // byte col in row
    const int sch  = (t & 3) * 8;               // short col (global)
    const size_t aBase = (size_t)(o0 + srow) * C + sch;
    const size_t bBase = ((size_t)b * Npad + n0 + srow) * C + sch;
    const size_t rstep = (size_t)64 * C;

    bf16x8 rA[2], rAl[2], rB[2], rBl[2];
    #pragma unroll
    for (int p = 0; p < 2; ++p) {
        rA[p] = *(const bf16x8*)(Ag_hi + aBase + p * rstep);
        rB[p] = *(const bf16x8*)(Bg_hi + bBase + p * rstep);
        if constexpr (ALO) rAl[p] = *(const bf16x8*)(Ag_lo + aBase + p * rstep);
        if constexpr (BLO) rBl[p] = *(const bf16x8*)(Bg_lo + bBase + p * rstep);
    }

    for (int k0 = 0;; k0 += 32) {
        #pragma unroll
        for (int p = 0; p < 2; ++p) {
            int row = srow + p * 64;
            *(bf16x8*)((char*)Ah + SWZ(row, sbc)) = rA[p];
            *(bf16x8*)((char*)Bh + SWZ(row, sbc)) = rB[p];
            if constexpr (ALO) *(bf16x8*)((char*)Al + SWZ(row, sbc)) = rAl[p];
            if constexpr (BLO) *(bf16x8*)((char*)Bl + SWZ(row, sbc)) = rBl[p];
        }
        __syncthreads();

        if (k0 + 32 < C) {
            #pragma unroll
            for (int p = 0; p < 2; ++p) {
                rA[p] = *(const bf16x8*)(Ag_hi + aBase + (k0 + 32) + p * rstep);
                rB[p] = *(const bf16x8*)(Bg_hi + bBase + (k0 + 32) + p * rstep);
                if constexpr (ALO) rAl[p] = *(const bf16x8*)(Ag_lo + aBase + (k0 + 32) + p * rstep);
                if constexpr (BLO) rBl[p] = *(const bf16x8*)(Bg_lo + bBase + (k0 + 32) + p * rstep);
            }
        }

        bf16x8 ah[4], al[4];
        #pragma unroll
        for (int m = 0; m < 4; ++m) {
            int row = wm * 64 + m * 16 + lr;
            ah[m] = *(const bf16x8*)((char*)Ah + SWZ(row, kg * 16));
            if constexpr (ALO) al[m] = *(const bf16x8*)((char*)Al + SWZ(row, kg * 16));
        }
        #pragma unroll
        for (int nf = 0; nf < 4; ++nf) {
            int row = wn * 64 + nf * 16 + lr;
            bf16x8 bh = *(const bf16x8*)((char*)Bh + SWZ(row, kg * 16));
            #pragma unroll
            for (int m = 0; m < 4; ++m) {
                acc[m][nf] = MFMA32(ah[m], bh, acc[m][nf]);
                if constexpr (ALO) acc[m][nf] = MFMA32(al[m], bh, acc[m][nf]);
            }
            if constexpr (BLO) {
                bf16x8 bl = *(const bf16x8*)((char*)Bl + SWZ(row, kg * 16));
                #pragma unroll
                for (int m = 0; m < 4; ++m)
                    acc[m][nf] = MFMA32(ah[m], bl, acc[m][nf]);
            }
        }
        if (k0 + 32 >= C) break;
        __syncthreads();
    }

    #pragma unroll
    for (int m = 0; m < 4; ++m) {
        #pragma unroll
        for (int nf = 0; nf < 4; ++nf) {
            int col = n0 + wn * 64 + nf * 16 + lr;
            if (mode == 0) {
                if (col >= Nn) continue;
                #pragma unroll
                for (int r = 0; r < 4; ++r) {
                    int row = o0 + wm * 64 + m * 16 + kg * 4 + r;
                    float a = s[row];
                    out_f[((size_t)b * O + row) * Nn + col] =
                        acc[m][nf][r] * a + (bias[row] * a + off[row]);
                }
            } else if (mode == 1) {
                if (col >= NPADo) continue;
                #pragma unroll
                for (int r = 0; r < 4; ++r) {
                    int row = o0 + wm * 64 + m * 16 + kg * 4 + r;
                    short hv = 0;
                    if (col < Nn) {
                        float a = s[row];
                        hv = f2bf(acc[m][nf][r] * a + (bias[row] * a + off[row]));
                    }
                    out_b[((size_t)b * O + row) * NPADo + col] = hv;
                }
            } else {
                if (col >= NPADo) continue;
                int hh = (o0 + wm * 64 + m * 16) >> 4;
                short4 h4, l4;
                #pragma unroll
                for (int r = 0; r < 4; ++r) {
                    int row = o0 + wm * 64 + m * 16 + kg * 4 + r;
                    float v = 0.f;
                    if (col < Nn) {
                        float a = s[row];
                        v = (acc[m][nf][r] * a + (bias[row] * a + off[row])) * pscale;
                    }
                    short hv = f2bf(v);
                    ((short*)&h4)[r] = hv;
                    ((short*)&l4)[r] = f2bf(v - bf2f(hv));
                }
                size_t base = ((size_t)(b * 8 + hh) * NPADo + col) * 32 + kg * 4;
                *(short4*)(out_b + base)      = h4;
                *(short4*)(out_b + base + 16) = l4;
            }
        }
    }
}

// ---------------- v_local ----------------
__global__ void vlocal_kernel(const short* __restrict__ v,
                              const float* __restrict__ vl_w, const float* __restrict__ vl_b,
                              const float* __restrict__ vl_s, const float* __restrict__ vl_o,
                              float* __restrict__ vlocal) {
    int c = blockIdx.x, b = blockIdx.y, n2 = threadIdx.x;
    if (n2 >= NN2) return;
    int i = n2 / RES2, j = n2 % RES2;
    const size_t base = ((size_t)b * DH + c) * KPAD;
    const float* w = vl_w + c * 9;
    float acc = vl_b[c];
    #pragma unroll
    for (int di = 0; di < 3; ++di) {
        int r = 2 * i + di - 1;
        if (r < 0 || r >= RES) continue;
        #pragma unroll
        for (int dj = 0; dj < 3; ++dj) {
            int cc = 2 * j + dj - 1;
            if (cc < 0 || cc >= RES) continue;
            acc += bf2f(v[base + r * RES + cc]) * w[di * 3 + dj];
        }
    }
    vlocal[((size_t)b * DH + c) * NN2 + n2] = acc * vl_s[c] + vl_o[c];
}

// ---------------- bias expand -> bf16, padded rows of 832 ----------------
__global__ void biasB_expand_kernel(const float* __restrict__ ab, const int* __restrict__ bidx,
                                    short* __restrict__ biasB, int n_off) {
    int i = blockIdx.x * 256 + threadIdx.x;
    int h = blockIdx.y;
    if (i >= NN2 * KPAD) return;
    int q = i / KPAD, key = i - q * KPAD;
    short v = 0;
    if (key < NN) v = f2bf(ab[h * n_off + bidx[q * NN + key]]);
    biasB[(size_t)h * NN2 * KPAD + i] = v;
}

// ---------------- MFMA attention v7: 64 queries/wave, 1 block per (b,h) ----------------
__global__ __launch_bounds__(256)
void attn_mfma7_kernel(const short* __restrict__ QT, const short* __restrict__ KT,
                       const short* __restrict__ V, const short* __restrict__ biasB,
                       float* __restrict__ outT) {
    __shared__ __align__(16) char Ps[4][4][2048];

    const int t = threadIdx.x;
    const int bid = blockIdx.x;
    const int h = bid & 7;
    const int b = bid >> 3;

    const int lane = t & 63, wid = t >> 6;
    const int lr = lane & 15, kg = lane >> 4;
    const int wq0 = wid * 64;

    bf16x8 qb1[4], qb2[4];
    #pragma unroll
    for (int qf = 0; qf < 4; ++qf) {
        int qg = wq0 + qf * 16 + lr;
        const short* qrow = QT + ((size_t)(b * 8 + h) * QPAD + qg) * 32;
        qb1[qf] = *(const bf16x8*)(qrow + (kg & 1) * 8);
        qb2[qf] = (bf16x8){0, 0, 0, 0, 0, 0, 0, 0};
        if (kg < 2) qb2[qf] = *(const bf16x8*)(qrow + 16 + kg * 8);
    }

    const short* kbase = KT + (size_t)(b * 8 + h) * KPAD * 32;
    const short* vbase = V + ((size_t)b * DH + h * DD) * KPAD;
    const short* bb[4];
    #pragma unroll
    for (int qf = 0; qf < 4; ++qf) {
        int qg = wq0 + qf * 16 + lr;
        int qs = (qg < NN2) ? qg : (NN2 - 1);
        bb[qf] = biasB + ((size_t)h * NN2 + qs) * KPAD;
    }

    f32x4 acc[4][4];
    #pragma unroll
    for (int qf = 0; qf < 4; ++qf)
        #pragma unroll
        for (int nt = 0; nt < 4; ++nt)
            acc[qf][nt] = (f32x4){0.f, 0.f, 0.f, 0.f};
    float sacc[4] = {0.f, 0.f, 0.f, 0.f};
    char* PsBase = &Ps[wid][0][0];
    const int swz = (lr & 7) << 4;

    bf16x8 kaA[4], kaB[4];

    auto LOADK = [&](int tile, bf16x8* ka) {
        int k0 = tile * 64;
        #pragma unroll
        for (int nt = 0; nt < 4; ++nt)
            ka[nt] = *(const bf16x8*)(kbase + (size_t)(k0 + nt * 16 + lr) * 32 + kg * 8);
    };

    auto COMPUTE = [&](int tile, bf16x8* ka) {
        const int k0 = tile * 64;
        bf16x8 vf[8];
        #pragma unroll
        for (int ks = 0; ks < 2; ++ks)
            #pragma unroll
            for (int nt = 0; nt < 4; ++nt)
                vf[ks * 4 + nt] = *(const bf16x8*)(vbase + (size_t)(nt * 16 + lr) * KPAD
                                                   + k0 + ks * 32 + kg * 8);
        short4 b4[4][4];
        #pragma unroll
        for (int qf = 0; qf < 4; ++qf)
            #pragma unroll
            for (int nt = 0; nt < 4; ++nt)
                b4[qf][nt] = *(const short4*)(bb[qf] + k0 + nt * 16 + kg * 4);

        #pragma unroll
        for (int qf = 0; qf < 4; ++qf) {
            f32x4 sc[4];
            __builtin_amdgcn_s_setprio(1);
            #pragma unroll
            for (int nt = 0; nt < 4; ++nt) {
                sc[nt] = (f32x4){0.f, 0.f, 0.f, 0.f};
                sc[nt] = MFMA32(ka[nt], qb1[qf], sc[nt]);
                sc[nt] = MFMA32(ka[nt], qb2[qf], sc[nt]);
            }
            __builtin_amdgcn_s_setprio(0);

            if (qf == 3 && tile + 2 <= 12) LOADK(tile + 2, ka);

            char* Psw = PsBase + qf * 2048;
            #pragma unroll
            for (int nt = 0; nt < 4; ++nt) {
                int keyb = k0 + nt * 16 + kg * 4;
                bool kvalid = keyb < NN;
                short4 pk;
                #pragma unroll
                for (int r = 0; r < 4; ++r) {
                    float sv = sc[nt][r] + bf2f(((const short*)&b4[qf][nt])[r]);
                    float pv = kvalid ? __expf(sv) : 0.f;
                    sacc[qf] += pv;
                    ((short*)&pk)[r] = f2bf(pv);
                }
                *(short4*)(Psw + lr * 128 + ((nt * 32 + kg * 8) ^ swz)) = pk;
            }
            #pragma unroll
            for (int ks = 0; ks < 2; ++ks) {
                bf16x8 pa = *(const bf16x8*)(Psw + lr * 128 + ((ks * 64 + kg * 16) ^ swz));
                __builtin_amdgcn_s_setprio(1);
                #pragma unroll
                for (int nt = 0; nt < 4; ++nt)
                    acc[qf][nt] = MFMA32(pa, vf[ks * 4 + nt], acc[qf][nt]);
                __builtin_amdgcn_s_setprio(0);
            }
        }
    };

    LOADK(0, kaA);
    LOADK(1, kaB);
    #pragma unroll 1
    for (int tile = 0; tile < 12; tile += 2) {
        COMPUTE(tile,     kaA);
        COMPUTE(tile + 1, kaB);
    }
    COMPUTE(12, kaA);

    #pragma unroll
    for (int qf = 0; qf < 4; ++qf) {
        float sv = sacc[qf];
        sv += __shfl_xor(sv, 16, 64);
        sv += __shfl_xor(sv, 32, 64);
        #pragma unroll
        for (int r = 0; r < 4; ++r) {
            int qrow_ = wq0 + qf * 16 + kg * 4 + r;
            if (qrow_ >= NN2) continue;
            float inv = 1.f / __shfl(sv, kg * 4 + r, 64);
            #pragma unroll
            for (int nt = 0; nt < 4; ++nt) {
                int d = nt * 16 + lr;
                outT[((size_t)b * NN2 + qrow_) * DH + h * DD + d] = acc[qf][nt][r] * inv;
            }
        }
    }
}

// ---------------- gelu(attnT + vlocal^T) -> gT hi/lo [b][256][512] ----------------
__global__ void gelu_addT_kernel(const float* __restrict__ aT, const float* __restrict__ vloc,
                                 short* __restrict__ g_hi, short* __restrict__ g_lo) {
    __shared__ float tile[32][33];
    int ntb = blockIdx.x * 32, ctb = blockIdx.y * 32, b = blockIdx.z;
    int tn = threadIdx.x & 31, tc4 = threadIdx.x >> 5;
    #pragma unroll
    for (int i = 0; i < 4; ++i) {
        int c = tc4 + i * 8;
        int n = ntb + tn;
        tile[c][tn] = (n < NN2) ? vloc[((size_t)b * DH + ctb + c) * NN2 + n] : 0.f;
    }
    __syncthreads();
    int tc = threadIdx.x & 31, tn4 = threadIdx.x >> 5;
    #pragma unroll
    for (int i = 0; i < 4; ++i) {
        int n = ntb + tn4 + i * 8;
        float g = 0.f;
        if (n < NN2) {
            float sum = aT[((size_t)b * NN2 + n) * DH + ctb + tc] + tile[tc][tn4 + i * 8];
            g = 0.5f * sum * (1.f + erff(sum * 0.70710678118654752440f));
        }
        short hh = f2bf(g);
        size_t o = ((size_t)b * QPAD + n) * DH + ctb + tc;
        g_hi[o] = hh;
        g_lo[o] = f2bf(g - bf2f(hh));
    }
}

extern "C" void kernel_launch(void* const* d_in, const int* in_sizes, int n_in,
                              void* d_out, int out_size, void* d_ws, size_t ws_size,
                              hipStream_t stream) {
    const float* x     = (const float*)d_in[0];
    const float* ql_w  = (const float*)d_in[1];
    const float* ql_b  = (const float*)d_in[2];
    const float* qp_w  = (const float*)d_in[3];
    const float* qp_b  = (const float*)d_in[4];
    const float* qp_s  = (const float*)d_in[5];
    const float* qp_o  = (const float*)d_in[6];
    const float* k_w   = (const float*)d_in[7];
    const float* k_b   = (const float*)d_in[8];
    const float* k_s   = (const float*)d_in[9];
    const float* k_o   = (const float*)d_in[10];
    const float* v_w   = (const float*)d_in[11];
    const float* v_b   = (const float*)d_in[12];
    const float* v_s   = (const float*)d_in[13];
    const float* v_o   = (const float*)d_in[14];
    const float* vl_w  = (const float*)d_in[15];
    const float* vl_b  = (const float*)d_in[16];
    const float* vl_s  = (const float*)d_in[17];
    const float* vl_o  = (const float*)d_in[18];
    const float* p_w   = (const float*)d_in[19];
    const float* p_b   = (const float*)d_in[20];
    const float* p_s   = (const float*)d_in[21];
    const float* p_o   = (const float*)d_in[22];
    const float* ab    = (const float*)d_in[23];
    const int*   bidx  = (const int*)d_in[24];
    float* out = (float*)d_out;
    int n_off = in_sizes[23] / HEADS;

    char* ws = (char*)d_ws;
    short* qinT_h = (short*)(ws + O_QINT_HI);
    short* xT_h   = (short*)(ws + O_XT_HI);
    short* QT     = (short*)(ws + O_QT);
    short* KT     = (short*)(ws + O_KT);
    short* Vb     = (short*)(ws + O_V);
    float* vlocal = (float*)(ws + O_VLOCAL);
    short* biasB  = (short*)(ws + O_BIASB);
    short* w_h    = (short*)(ws + O_W_HI);
    short* w_l    = (short*)(ws + O_W_LO);
    float* attnT  = (float*)(ws + O_ATTNT);
    short* gT_h   = (short*)(ws + O_GT_HI);
    short* gT_l   = (short*)(ws + O_GT_LO);

    // 1. qin fused: dwconv+pool -> transposed bf16
    qinT_kernel<<<dim3(DIMC, BATCH), 256, 0, stream>>>(x, ql_w, ql_b, qinT_h);
    // 2. weight splits
    wsplit_kernel<<<dim3(1920), 256, 0, stream>>>(qp_w, k_w, v_w, p_w, w_h, w_l);
    // 3. q projection -> QT packed (pre-scaled by SCALE), weights RN-bf16 only
    gemm_split_kernel<false, false><<<dim3(2, 1, BATCH), 256, 0, stream>>>(
        w_h + 0, nullptr, qinT_h, nullptr, qp_b, qp_s, qp_o,
        nullptr, QT, 2, DIMC, NN2, QPAD, QPAD, SCALE);
    // 4. x -> xT (bf16)
    tsplit_kernel<<<dim3(XPAD / 32, DIMC / 32, BATCH), 256, 0, stream>>>(x, xT_h, DIMC, NN, XPAD);
    // 5. k projection -> KT packed
    gemm_split_kernel<false, false><<<dim3(7, 1, BATCH), 256, 0, stream>>>(
        w_h + 49152, nullptr, xT_h, nullptr, k_b, k_s, k_o,
        nullptr, KT, 2, DIMC, NN, XPAD, KPAD, 1.0f);
    // 6. v projection -> bf16 [b][512][832]
    gemm_split_kernel<false, false><<<dim3(7, 4, BATCH), 256, 0, stream>>>(
        w_h + 98304, nullptr, xT_h, nullptr, v_b, v_s, v_o,
        nullptr, Vb, 1, DIMC, NN, XPAD, KPAD, 1.0f);
    // 7. v_local
    vlocal_kernel<<<dim3(DH, BATCH), 256, 0, stream>>>(Vb, vl_w, vl_b, vl_s, vl_o, vlocal);
    // 8. bias expand
    biasB_expand_kernel<<<dim3((NN2 * KPAD + 255) / 256, HEADS), 256, 0, stream>>>(ab, bidx, biasB, n_off);
    // 9. attention
    attn_mfma7_kernel<<<dim3(HEADS * BATCH), 256, 0, stream>>>(QT, KT, Vb, biasB, attnT);
    // 10. gelu
    gelu_addT_kernel<<<dim3(QPAD / 32, DH / 32, BATCH), 256, 0, stream>>>(attnT, vlocal, gT_h, gT_l);
    // 11. output projection (full 3-term split for accuracy)
    gemm_split_kernel<true, true><<<dim3(2, 3, BATCH), 256, 0, stream>>>(
        w_h + 294912, w_l + 294912, gT_h, gT_l, p_b, p_s, p_o,
        out, nullptr, 0, DH, NN2, QPAD, 0, 1.0f);
}

// Round 12
// 387.463 us; speedup vs baseline: 1.3059x; 1.0355x over previous
//
#include <hip/hip_runtime.h>
#include <math.h>

#define BATCH   64
#define DIMC    384
#define KEY_DIM 16
#define HEADS   8
#define DD      64
#define DH      512
#define NH_KD   128
#define RES     28
#define RES2    14
#define NN      784
#define NN2     196
#define OUT_DIM 384
#define SCALE   0.25f
#define XPAD    896     // 7*128
#define QPAD    256     // 2*128
#define KPAD    832     // 13*64

typedef __attribute__((ext_vector_type(8))) short bf16x8;
typedef __attribute__((ext_vector_type(4))) float f32x4;

#define MFMA32(a, b, c) __builtin_amdgcn_mfma_f32_16x16x32_bf16(a, b, c, 0, 0, 0)
// XOR swizzle: byte offset within 8KB tile; conflict-free fragment reads (verified R11: 0 conflicts)
#define SWZ(row, bcol) ((row) * 64 + ((bcol) ^ ((((row) >> 1) & 3) << 4)))

__device__ inline short f2bf(float f) {
    unsigned u = __float_as_uint(f);
    unsigned r = (u + 0x7fff + ((u >> 16) & 1)) >> 16;
    return (short)r;
}
__device__ inline float bf2f(short h) {
    return __uint_as_float(((unsigned)(unsigned short)h) << 16);
}
__device__ __forceinline__ void gload16(const void* g, void* l) {
    __builtin_amdgcn_global_load_lds((const __attribute__((address_space(1))) void*)g,
                                     (__attribute__((address_space(3))) void*)l, 16, 0, 0);
}

// ---- ws byte offsets ----
#define O_QINT_HI  20971520u
#define O_XT_HI    0u
#define O_QT       88080384u
#define O_KT       96468992u
#define O_V        123731968u
#define O_VLOCAL   178257920u
#define O_BIASB    203948032u
#define O_W_HI     206557184u
#define O_W_LO     207540224u
#define O_ATTNT    0u
#define O_GT_HI    25690112u
#define O_GT_LO    42467328u

// ---------------- qinT = f2bf(dwconv3x3 s2 (pad 1) + pool), transposed [b][QPAD][C] ----------------
__global__ void qinT_kernel(const float* __restrict__ x, const float* __restrict__ ql_w,
                            const float* __restrict__ ql_b, short* __restrict__ qinT) {
    int c = blockIdx.x, b = blockIdx.y, n2 = threadIdx.x;
    if (n2 >= NN2) return;
    int i = n2 / RES2, j = n2 % RES2;
    const float* xp = x + ((size_t)b * DIMC + c) * (RES * RES);
    const float* w  = ql_w + c * 9;
    float acc = ql_b[c];
    #pragma unroll
    for (int di = 0; di < 3; ++di) {
        int r = 2 * i + di - 1;
        if (r < 0 || r >= RES) continue;
        #pragma unroll
        for (int dj = 0; dj < 3; ++dj) {
            int cc = 2 * j + dj - 1;
            if (cc < 0 || cc >= RES) continue;
            acc += xp[r * RES + cc] * w[di * 3 + dj];
        }
    }
    acc += xp[(2 * i) * RES + 2 * j];
    qinT[((size_t)b * QPAD + n2) * DIMC + c] = f2bf(acc);
}

// ---------------- weight split ----------------
__global__ void wsplit_kernel(const float* __restrict__ w0, const float* __restrict__ w1,
                              const float* __restrict__ w2, const float* __restrict__ w3,
                              short* __restrict__ hi, short* __restrict__ lo) {
    int i = blockIdx.x * 256 + threadIdx.x;
    if (i >= 491520) return;
    const float* src; int j = i;
    if (j < 49152) src = w0;
    else if (j < 98304) { src = w1; j -= 49152; }
    else if (j < 294912) { src = w2; j -= 98304; }
    else { src = w3; j -= 294912; }
    float v = src[j];
    short h = f2bf(v);
    hi[i] = h;
    lo[i] = f2bf(v - bf2f(h));
}

// ---------------- transpose + bf16: [b][C][N] f32 -> [b][Npad][C] bf16 ----------------
__global__ void tsplit_kernel(const float* __restrict__ in, short* __restrict__ out_hi,
                              int C, int N, int Npad) {
    __shared__ float tile[32][33];
    int ntb = blockIdx.x * 32, ctb = blockIdx.y * 32, b = blockIdx.z;
    int tn = threadIdx.x & 31, tc4 = threadIdx.x >> 5;
    #pragma unroll
    for (int i = 0; i < 4; ++i) {
        int c = tc4 + i * 8;
        int n = ntb + tn;
        tile[c][tn] = (n < N) ? in[((size_t)b * C + ctb + c) * N + n] : 0.f;
    }
    __syncthreads();
    int tc = threadIdx.x & 31, tn4 = threadIdx.x >> 5;
    #pragma unroll
    for (int i = 0; i < 4; ++i) {
        int n = tn4 + i * 8;
        out_hi[((size_t)b * Npad + ntb + n) * C + ctb + tc] = f2bf(tile[tc][n]);
    }
}

// ---------------- bf16 MFMA GEMM: global_load_lds + double-buffered LDS ----------------
// A = weights hi (+lo if ALO); B = activations hi (+lo if BLO)
// LDS linear (gload_lds dest), swizzle applied on the per-lane GLOBAL source address;
// fragment reads use the same SWZ -> conflict-free (verified 0 conflicts in R11).
// mode 0: fp32 [b][O][Nn]; mode 1: bf16 [b][O][NPADo] zero-padded;
// mode 2: packed [b*8+h][NPADo][16hi|16lo] (O=128), scaled by pscale
template<bool ALO, bool BLO>
__global__ __launch_bounds__(256)
void gemm_split_kernel(const short* __restrict__ Ag_hi, const short* __restrict__ Ag_lo,
                       const short* __restrict__ Bg_hi, const short* __restrict__ Bg_lo,
                       const float* __restrict__ bias, const float* __restrict__ s,
                       const float* __restrict__ off,
                       float* __restrict__ out_f, short* __restrict__ out_b,
                       int mode, int C, int Nn, int Npad, int NPADo, float pscale) {
    constexpr int NT = 2 + (ALO ? 1 : 0) + (BLO ? 1 : 0);
    constexpr int STRIDE = NT * 8192;
    constexpr int OFF_AH = 0, OFF_BH = 8192;
    constexpr int OFF_AL = 16384;
    constexpr int OFF_BL = 16384 + (ALO ? 8192 : 0);
    __shared__ __align__(1024) char LDS[2 * STRIDE];

    const int t = threadIdx.x;
    const int n0 = blockIdx.x * 128, o0 = blockIdx.y * 128, b = blockIdx.z;
    const int O = gridDim.y * 128;
    const int lane = t & 63, wid = t >> 6;
    const int wm = wid & 1, wn = wid >> 1;
    const int lr = lane & 15, kg = lane >> 4;

    f32x4 acc[4][4];
    #pragma unroll
    for (int m = 0; m < 4; ++m)
        #pragma unroll
        for (int n = 0; n < 4; ++n)
            acc[m][n] = (f32x4){0.f, 0.f, 0.f, 0.f};

    // staging geometry: wave covers rows [wid*32, wid*32+32), 2 chunks of 16 rows (1KB each)
    const int ccol = (lane & 3) * 16;          // byte col within 64B row
    const int r0   = wid * 32 + (lane >> 2);   // + c*16

    auto STAGE = [&](int buf, int k0) {
        char* base = LDS + buf * STRIDE;
        #pragma unroll
        for (int c = 0; c < 2; ++c) {
            int r = r0 + c * 16;
            int bcs = ccol ^ (((r >> 1) & 3) << 4);    // pre-swizzled source col
            size_t arow = ((size_t)(o0 + r) * C + k0) * 2 + bcs;
            size_t brow = (((size_t)b * Npad + n0 + r) * C + k0) * 2 + bcs;
            char* ldsc = base + wid * 2048 + c * 1024;  // wave-uniform
            gload16((const char*)Ag_hi + arow, ldsc + OFF_AH);
            gload16((const char*)Bg_hi + brow, ldsc + OFF_BH);
            if constexpr (ALO) gload16((const char*)Ag_lo + arow, ldsc + OFF_AL);
            if constexpr (BLO) gload16((const char*)Bg_lo + brow, ldsc + OFF_BL);
        }
    };

    STAGE(0, 0);
    int cur = 0;
    __syncthreads();

    for (int k0 = 0;; k0 += 32) {
        const bool hasNext = (k0 + 32 < C);
        if (hasNext) STAGE(cur ^ 1, k0 + 32);

        char* cb = LDS + cur * STRIDE;
        bf16x8 ah[4], al[4];
        #pragma unroll
        for (int m = 0; m < 4; ++m) {
            int row = wm * 64 + m * 16 + lr;
            ah[m] = *(const bf16x8*)(cb + OFF_AH + SWZ(row, kg * 16));
            if constexpr (ALO) al[m] = *(const bf16x8*)(cb + OFF_AL + SWZ(row, kg * 16));
        }
        #pragma unroll
        for (int nf = 0; nf < 4; ++nf) {
            int row = wn * 64 + nf * 16 + lr;
            bf16x8 bh = *(const bf16x8*)(cb + OFF_BH + SWZ(row, kg * 16));
            #pragma unroll
            for (int m = 0; m < 4; ++m) {
                acc[m][nf] = MFMA32(ah[m], bh, acc[m][nf]);
                if constexpr (ALO) acc[m][nf] = MFMA32(al[m], bh, acc[m][nf]);
            }
            if constexpr (BLO) {
                bf16x8 bl = *(const bf16x8*)(cb + OFF_BL + SWZ(row, kg * 16));
                #pragma unroll
                for (int m = 0; m < 4; ++m)
                    acc[m][nf] = MFMA32(ah[m], bl, acc[m][nf]);
            }
        }
        if (!hasNext) break;
        __syncthreads();
        cur ^= 1;
    }

    #pragma unroll
    for (int m = 0; m < 4; ++m) {
        #pragma unroll
        for (int nf = 0; nf < 4; ++nf) {
            int col = n0 + wn * 64 + nf * 16 + lr;
            if (mode == 0) {
                if (col >= Nn) continue;
                #pragma unroll
                for (int r = 0; r < 4; ++r) {
                    int row = o0 + wm * 64 + m * 16 + kg * 4 + r;
                    float a = s[row];
                    out_f[((size_t)b * O + row) * Nn + col] =
                        acc[m][nf][r] * a + (bias[row] * a + off[row]);
                }
            } else if (mode == 1) {
                if (col >= NPADo) continue;
                #pragma unroll
                for (int r = 0; r < 4; ++r) {
                    int row = o0 + wm * 64 + m * 16 + kg * 4 + r;
                    short hv = 0;
                    if (col < Nn) {
                        float a = s[row];
                        hv = f2bf(acc[m][nf][r] * a + (bias[row] * a + off[row]));
                    }
                    out_b[((size_t)b * O + row) * NPADo + col] = hv;
                }
            } else {
                if (col >= NPADo) continue;
                int hh = (o0 + wm * 64 + m * 16) >> 4;
                short4 h4, l4;
                #pragma unroll
                for (int r = 0; r < 4; ++r) {
                    int row = o0 + wm * 64 + m * 16 + kg * 4 + r;
                    float v = 0.f;
                    if (col < Nn) {
                        float a = s[row];
                        v = (acc[m][nf][r] * a + (bias[row] * a + off[row])) * pscale;
                    }
                    short hv = f2bf(v);
                    ((short*)&h4)[r] = hv;
                    ((short*)&l4)[r] = f2bf(v - bf2f(hv));
                }
                size_t base = ((size_t)(b * 8 + hh) * NPADo + col) * 32 + kg * 4;
                *(short4*)(out_b + base)      = h4;
                *(short4*)(out_b + base + 16) = l4;
            }
        }
    }
}

// ---------------- v_local ----------------
__global__ void vlocal_kernel(const short* __restrict__ v,
                              const float* __restrict__ vl_w, const float* __restrict__ vl_b,
                              const float* __restrict__ vl_s, const float* __restrict__ vl_o,
                              float* __restrict__ vlocal) {
    int c = blockIdx.x, b = blockIdx.y, n2 = threadIdx.x;
    if (n2 >= NN2) return;
    int i = n2 / RES2, j = n2 % RES2;
    const size_t base = ((size_t)b * DH + c) * KPAD;
    const float* w = vl_w + c * 9;
    float acc = vl_b[c];
    #pragma unroll
    for (int di = 0; di < 3; ++di) {
        int r = 2 * i + di - 1;
        if (r < 0 || r >= RES) continue;
        #pragma unroll
        for (int dj = 0; dj < 3; ++dj) {
            int cc = 2 * j + dj - 1;
            if (cc < 0 || cc >= RES) continue;
            acc += bf2f(v[base + r * RES + cc]) * w[di * 3 + dj];
        }
    }
    vlocal[((size_t)b * DH + c) * NN2 + n2] = acc * vl_s[c] + vl_o[c];
}

// ---------------- bias expand -> bf16, padded rows of 832 ----------------
__global__ void biasB_expand_kernel(const float* __restrict__ ab, const int* __restrict__ bidx,
                                    short* __restrict__ biasB, int n_off) {
    int i = blockIdx.x * 256 + threadIdx.x;
    int h = blockIdx.y;
    if (i >= NN2 * KPAD) return;
    int q = i / KPAD, key = i - q * KPAD;
    short v = 0;
    if (key < NN) v = f2bf(ab[h * n_off + bidx[q * NN + key]]);
    biasB[(size_t)h * NN2 * KPAD + i] = v;
}

// ---------------- MFMA attention v7: 64 queries/wave, 1 block per (b,h) ----------------
__global__ __launch_bounds__(256)
void attn_mfma7_kernel(const short* __restrict__ QT, const short* __restrict__ KT,
                       const short* __restrict__ V, const short* __restrict__ biasB,
                       float* __restrict__ outT) {
    __shared__ __align__(16) char Ps[4][4][2048];

    const int t = threadIdx.x;
    const int bid = blockIdx.x;
    const int h = bid & 7;
    const int b = bid >> 3;

    const int lane = t & 63, wid = t >> 6;
    const int lr = lane & 15, kg = lane >> 4;
    const int wq0 = wid * 64;

    bf16x8 qb1[4], qb2[4];
    #pragma unroll
    for (int qf = 0; qf < 4; ++qf) {
        int qg = wq0 + qf * 16 + lr;
        const short* qrow = QT + ((size_t)(b * 8 + h) * QPAD + qg) * 32;
        qb1[qf] = *(const bf16x8*)(qrow + (kg & 1) * 8);
        qb2[qf] = (bf16x8){0, 0, 0, 0, 0, 0, 0, 0};
        if (kg < 2) qb2[qf] = *(const bf16x8*)(qrow + 16 + kg * 8);
    }

    const short* kbase = KT + (size_t)(b * 8 + h) * KPAD * 32;
    const short* vbase = V + ((size_t)b * DH + h * DD) * KPAD;
    const short* bb[4];
    #pragma unroll
    for (int qf = 0; qf < 4; ++qf) {
        int qg = wq0 + qf * 16 + lr;
        int qs = (qg < NN2) ? qg : (NN2 - 1);
        bb[qf] = biasB + ((size_t)h * NN2 + qs) * KPAD;
    }

    f32x4 acc[4][4];
    #pragma unroll
    for (int qf = 0; qf < 4; ++qf)
        #pragma unroll
        for (int nt = 0; nt < 4; ++nt)
            acc[qf][nt] = (f32x4){0.f, 0.f, 0.f, 0.f};
    float sacc[4] = {0.f, 0.f, 0.f, 0.f};
    char* PsBase = &Ps[wid][0][0];
    const int swz = (lr & 7) << 4;

    bf16x8 kaA[4], kaB[4];

    auto LOADK = [&](int tile, bf16x8* ka) {
        int k0 = tile * 64;
        #pragma unroll
        for (int nt = 0; nt < 4; ++nt)
            ka[nt] = *(const bf16x8*)(kbase + (size_t)(k0 + nt * 16 + lr) * 32 + kg * 8);
    };

    auto COMPUTE = [&](int tile, bf16x8* ka) {
        const int k0 = tile * 64;
        bf16x8 vf[8];
        #pragma unroll
        for (int ks = 0; ks < 2; ++ks)
            #pragma unroll
            for (int nt = 0; nt < 4; ++nt)
                vf[ks * 4 + nt] = *(const bf16x8*)(vbase + (size_t)(nt * 16 + lr) * KPAD
                                                   + k0 + ks * 32 + kg * 8);
        short4 b4[4][4];
        #pragma unroll
        for (int qf = 0; qf < 4; ++qf)
            #pragma unroll
            for (int nt = 0; nt < 4; ++nt)
                b4[qf][nt] = *(const short4*)(bb[qf] + k0 + nt * 16 + kg * 4);

        #pragma unroll
        for (int qf = 0; qf < 4; ++qf) {
            f32x4 sc[4];
            __builtin_amdgcn_s_setprio(1);
            #pragma unroll
            for (int nt = 0; nt < 4; ++nt) {
                sc[nt] = (f32x4){0.f, 0.f, 0.f, 0.f};
                sc[nt] = MFMA32(ka[nt], qb1[qf], sc[nt]);
                sc[nt] = MFMA32(ka[nt], qb2[qf], sc[nt]);
            }
            __builtin_amdgcn_s_setprio(0);

            if (qf == 3 && tile + 2 <= 12) LOADK(tile + 2, ka);

            char* Psw = PsBase + qf * 2048;
            #pragma unroll
            for (int nt = 0; nt < 4; ++nt) {
                int keyb = k0 + nt * 16 + kg * 4;
                bool kvalid = keyb < NN;
                short4 pk;
                #pragma unroll
                for (int r = 0; r < 4; ++r) {
                    float sv = sc[nt][r] + bf2f(((const short*)&b4[qf][nt])[r]);
                    float pv = kvalid ? __expf(sv) : 0.f;
                    sacc[qf] += pv;
                    ((short*)&pk)[r] = f2bf(pv);
                }
                *(short4*)(Psw + lr * 128 + ((nt * 32 + kg * 8) ^ swz)) = pk;
            }
            #pragma unroll
            for (int ks = 0; ks < 2; ++ks) {
                bf16x8 pa = *(const bf16x8*)(Psw + lr * 128 + ((ks * 64 + kg * 16) ^ swz));
                __builtin_amdgcn_s_setprio(1);
                #pragma unroll
                for (int nt = 0; nt < 4; ++nt)
                    acc[qf][nt] = MFMA32(pa, vf[ks * 4 + nt], acc[qf][nt]);
                __builtin_amdgcn_s_setprio(0);
            }
        }
    };

    LOADK(0, kaA);
    LOADK(1, kaB);
    #pragma unroll 1
    for (int tile = 0; tile < 12; tile += 2) {
        COMPUTE(tile,     kaA);
        COMPUTE(tile + 1, kaB);
    }
    COMPUTE(12, kaA);

    #pragma unroll
    for (int qf = 0; qf < 4; ++qf) {
        float sv = sacc[qf];
        sv += __shfl_xor(sv, 16, 64);
        sv += __shfl_xor(sv, 32, 64);
        #pragma unroll
        for (int r = 0; r < 4; ++r) {
            int qrow_ = wq0 + qf * 16 + kg * 4 + r;
            if (qrow_ >= NN2) continue;
            float inv = 1.f / __shfl(sv, kg * 4 + r, 64);
            #pragma unroll
            for (int nt = 0; nt < 4; ++nt) {
                int d = nt * 16 + lr;
                outT[((size_t)b * NN2 + qrow_) * DH + h * DD + d] = acc[qf][nt][r] * inv;
            }
        }
    }
}

// ---------------- gelu(attnT + vlocal^T) -> gT hi/lo [b][256][512] ----------------
__global__ void gelu_addT_kernel(const float* __restrict__ aT, const float* __restrict__ vloc,
                                 short* __restrict__ g_hi, short* __restrict__ g_lo) {
    __shared__ float tile[32][33];
    int ntb = blockIdx.x * 32, ctb = blockIdx.y * 32, b = blockIdx.z;
    int tn = threadIdx.x & 31, tc4 = threadIdx.x >> 5;
    #pragma unroll
    for (int i = 0; i < 4; ++i) {
        int c = tc4 + i * 8;
        int n = ntb + tn;
        tile[c][tn] = (n < NN2) ? vloc[((size_t)b * DH + ctb + c) * NN2 + n] : 0.f;
    }
    __syncthreads();
    int tc = threadIdx.x & 31, tn4 = threadIdx.x >> 5;
    #pragma unroll
    for (int i = 0; i < 4; ++i) {
        int n = ntb + tn4 + i * 8;
        float g = 0.f;
        if (n < NN2) {
            float sum = aT[((size_t)b * NN2 + n) * DH + ctb + tc] + tile[tc][tn4 + i * 8];
            g = 0.5f * sum * (1.f + erff(sum * 0.70710678118654752440f));
        }
        short hh = f2bf(g);
        size_t o = ((size_t)b * QPAD + n) * DH + ctb + tc;
        g_hi[o] = hh;
        g_lo[o] = f2bf(g - bf2f(hh));
    }
}

extern "C" void kernel_launch(void* const* d_in, const int* in_sizes, int n_in,
                              void* d_out, int out_size, void* d_ws, size_t ws_size,
                              hipStream_t stream) {
    const float* x     = (const float*)d_in[0];
    const float* ql_w  = (const float*)d_in[1];
    const float* ql_b  = (const float*)d_in[2];
    const float* qp_w  = (const float*)d_in[3];
    const float* qp_b  = (const float*)d_in[4];
    const float* qp_s  = (const float*)d_in[5];
    const float* qp_o  = (const float*)d_in[6];
    const float* k_w   = (const float*)d_in[7];
    const float* k_b   = (const float*)d_in[8];
    const float* k_s   = (const float*)d_in[9];
    const float* k_o   = (const float*)d_in[10];
    const float* v_w   = (const float*)d_in[11];
    const float* v_b   = (const float*)d_in[12];
    const float* v_s   = (const float*)d_in[13];
    const float* v_o   = (const float*)d_in[14];
    const float* vl_w  = (const float*)d_in[15];
    const float* vl_b  = (const float*)d_in[16];
    const float* vl_s  = (const float*)d_in[17];
    const float* vl_o  = (const float*)d_in[18];
    const float* p_w   = (const float*)d_in[19];
    const float* p_b   = (const float*)d_in[20];
    const float* p_s   = (const float*)d_in[21];
    const float* p_o   = (const float*)d_in[22];
    const float* ab    = (const float*)d_in[23];
    const int*   bidx  = (const int*)d_in[24];
    float* out = (float*)d_out;
    int n_off = in_sizes[23] / HEADS;

    char* ws = (char*)d_ws;
    short* qinT_h = (short*)(ws + O_QINT_HI);
    short* xT_h   = (short*)(ws + O_XT_HI);
    short* QT     = (short*)(ws + O_QT);
    short* KT     = (short*)(ws + O_KT);
    short* Vb     = (short*)(ws + O_V);
    float* vlocal = (float*)(ws + O_VLOCAL);
    short* biasB  = (short*)(ws + O_BIASB);
    short* w_h    = (short*)(ws + O_W_HI);
    short* w_l    = (short*)(ws + O_W_LO);
    float* attnT  = (float*)(ws + O_ATTNT);
    short* gT_h   = (short*)(ws + O_GT_HI);
    short* gT_l   = (short*)(ws + O_GT_LO);

    // 1. qin fused: dwconv+pool -> transposed bf16
    qinT_kernel<<<dim3(DIMC, BATCH), 256, 0, stream>>>(x, ql_w, ql_b, qinT_h);
    // 2. weight splits
    wsplit_kernel<<<dim3(1920), 256, 0, stream>>>(qp_w, k_w, v_w, p_w, w_h, w_l);
    // 3. q projection -> QT packed (pre-scaled by SCALE)
    gemm_split_kernel<false, false><<<dim3(2, 1, BATCH), 256, 0, stream>>>(
        w_h + 0, nullptr, qinT_h, nullptr, qp_b, qp_s, qp_o,
        nullptr, QT, 2, DIMC, NN2, QPAD, QPAD, SCALE);
    // 4. x -> xT (bf16)
    tsplit_kernel<<<dim3(XPAD / 32, DIMC / 32, BATCH), 256, 0, stream>>>(x, xT_h, DIMC, NN, XPAD);
    // 5. k projection -> KT packed
    gemm_split_kernel<false, false><<<dim3(7, 1, BATCH), 256, 0, stream>>>(
        w_h + 49152, nullptr, xT_h, nullptr, k_b, k_s, k_o,
        nullptr, KT, 2, DIMC, NN, XPAD, KPAD, 1.0f);
    // 6. v projection -> bf16 [b][512][832]
    gemm_split_kernel<false, false><<<dim3(7, 4, BATCH), 256, 0, stream>>>(
        w_h + 98304, nullptr, xT_h, nullptr, v_b, v_s, v_o,
        nullptr, Vb, 1, DIMC, NN, XPAD, KPAD, 1.0f);
    // 7. v_local
    vlocal_kernel<<<dim3(DH, BATCH), 256, 0, stream>>>(Vb, vl_w, vl_b, vl_s, vl_o, vlocal);
    // 8. bias expand
    biasB_expand_kernel<<<dim3((NN2 * KPAD + 255) / 256, HEADS), 256, 0, stream>>>(ab, bidx, biasB, n_off);
    // 9. attention
    attn_mfma7_kernel<<<dim3(HEADS * BATCH), 256, 0, stream>>>(QT, KT, Vb, biasB, attnT);
    // 10. gelu
    gelu_addT_kernel<<<dim3(QPAD / 32, DH / 32, BATCH), 256, 0, stream>>>(attnT, vlocal, gT_h, gT_l);
    // 11. output projection (full 3-term split for accuracy)
    gemm_split_kernel<true, true><<<dim3(2, 3, BATCH), 256, 0, stream>>>(
        w_h + 294912, w_l + 294912, gT_h, gT_l, p_b, p_s, p_o,
        out, nullptr, 0, DH, NN2, QPAD, 0, 1.0f);
}